// Round 18
// baseline (768.460 us; speedup 1.0000x reference)
//
#include <hip/hip_runtime.h>

#define NROWS 32768   // B*T = 16*2048
#define DIM 256
#define KCODES 1024
#define NLEV 4
#define CAP 64
#define MARGIN 8e-3f

typedef short short8v __attribute__((ext_vector_type(8)));
typedef float f32x4v  __attribute__((ext_vector_type(4)));

// bf16 round-to-nearest-even
static __device__ __forceinline__ unsigned short f2bf(float f) {
  unsigned u = __float_as_uint(f);
  unsigned lsb = (u >> 16) & 1u;
  u += 0x7fffu + lsb;
  return (unsigned short)(u >> 16);
}

// Packed fragment layout (per 16-row/16-code tile of 256 dims = 4096 shorts):
//   pak[tile][ks*512 + kb*128 + r8*8 + j] = elem(row = tile*16 + r8,
//                                               k = ks*32 + kb*8 + j)
// Wave reads short8v at pak + tile*4096 + ks*512 + lane*8 -> contiguous 1 KB.

// ============ codebook squared norms (unchanged, verified) ============
__global__ __launch_bounds__(256) void k_bnorm(const float* __restrict__ cb,
                                               float* __restrict__ bv) {
  int r = blockIdx.x * blockDim.x + threadIdx.x;
  if (r >= NLEV * KCODES) return;
  const float4* p = reinterpret_cast<const float4*>(cb + (size_t)r * DIM);
  float s0 = 0.f, s1 = 0.f, s2 = 0.f, s3 = 0.f;
  for (int g = 0; g < DIM / 4; ++g) {
    float4 v = p[g];
    s0 += v.x * v.x; s1 += v.y * v.y; s2 += v.z * v.z; s3 += v.w * v.w;
  }
  bv[r] = (s0 + s1) + (s2 + s3);
}

// ============ codebook -> bf16, PACKED fragment layout (verified r15) ============
__global__ __launch_bounds__(256) void k_csplit(const float* __restrict__ cb,
                                                unsigned short* __restrict__ chi) {
  const int tid = threadIdx.x;
  const int cr = blockIdx.x * 16 + (tid >> 4);
  const int l16 = tid & 15;
  const float4* p = reinterpret_cast<const float4*>(cb + (size_t)cr * DIM + l16 * 16);
  unsigned w[8];
  #pragma unroll
  for (int j = 0; j < 4; ++j) {
    float4 v = p[j];
    w[2 * j + 0] = (unsigned)f2bf(v.x) | ((unsigned)f2bf(v.y) << 16);
    w[2 * j + 1] = (unsigned)f2bf(v.z) | ((unsigned)f2bf(v.w) << 16);
  }
  const int lvl_ = cr >> 10;
  const int c = cr & 1023;
  unsigned short* base = chi + (size_t)lvl_ * (KCODES * DIM) + (size_t)(c >> 4) * 4096;
  const int c8 = c & 15;
  const int ks = l16 >> 1;
  const int kb0 = (l16 & 1) * 2;
  *reinterpret_cast<uint4*>(base + ks * 512 + kb0 * 128 + c8 * 8) =
      make_uint4(w[0], w[1], w[2], w[3]);
  *reinterpret_cast<uint4*>(base + ks * 512 + (kb0 + 1) * 128 + c8 * 8) =
      make_uint4(w[4], w[5], w[6], w[7]);
}

// ============ x -> rowsq + rhi (PACKED, verified r15) ============
__global__ __launch_bounds__(256) void k_prep(const float* __restrict__ x,
                                              unsigned short* __restrict__ rhi,
                                              float* __restrict__ rowsq) {
  __shared__ float sred[256];
  const int tid = threadIdx.x;
  const int rr = tid >> 4;
  const int l16 = tid & 15;
  const int row = blockIdx.x * 16 + rr;
  const float4* p = reinterpret_cast<const float4*>(x + (size_t)row * DIM + l16 * 16);
  float e = 0.f;
  unsigned w[8];
  #pragma unroll
  for (int j = 0; j < 4; ++j) {
    float4 v = p[j];
    e += v.x * v.x + v.y * v.y + v.z * v.z + v.w * v.w;
    w[2 * j + 0] = (unsigned)f2bf(v.x) | ((unsigned)f2bf(v.y) << 16);
    w[2 * j + 1] = (unsigned)f2bf(v.z) | ((unsigned)f2bf(v.w) << 16);
  }
  unsigned short* base = rhi + (size_t)blockIdx.x * 4096;
  const int ks = l16 >> 1;
  const int kb0 = (l16 & 1) * 2;
  *reinterpret_cast<uint4*>(base + ks * 512 + kb0 * 128 + rr * 8) =
      make_uint4(w[0], w[1], w[2], w[3]);
  *reinterpret_cast<uint4*>(base + ks * 512 + (kb0 + 1) * 128 + rr * 8) =
      make_uint4(w[4], w[5], w[6], w[7]);
  sred[tid] = e;
  __syncthreads();
  if (tid < 16) {
    float s = 0.f;
    #pragma unroll
    for (int k = 0; k < 16; ++k) s += sred[tid * 16 + k];
    rowsq[blockIdx.x * 16 + tid] = s;
  }
}

// ============ MFMA bf16 screen: 256-thr quarter-blocks, LDS dbuf ============
// 2048 blocks = 512 row-blocks (low bits, 64 rows) x 4 code-quarters (high
// bits -> same rows share an XCD). Wave = one 16-row tile x 256 codes:
// acc[16]=64 AGPR, staging 16 VGPR -> ~105 regs, LDS 32 KB -> ~4 blocks/CU of
// independent blocks (the TLP r15-r17 lacked). Per ks-step: issue 4x 1KB/wave
// staging loads + 1 A-load early, compute 16 ds_read_b128 (linear,
// conflict-free) + 16 MFMA, write-late, one barrier. Survivors vs quarter-
// local min + MARGIN (r16-validated: MARGIN >= 2*err), global atomic slots.
// Fragments bit-identical to r12-r17.
__global__ __launch_bounds__(256) void k_screen(const unsigned short* __restrict__ rhi,
                                                const unsigned short* __restrict__ chi_l,
                                                const float* __restrict__ bv_l,
                                                const float* __restrict__ rowsq,
                                                unsigned* __restrict__ survq,
                                                unsigned* __restrict__ counts_l) {
  __shared__ __align__(16) unsigned short Blds[2][8192];  // 2 x 16 KB
  const int tid = threadIdx.x;
  const int lane = tid & 63;
  const int w = tid >> 6;          // wave = row-tile 0..3
  const int rb = blockIdx.x & 511; // row block (64 rows)
  const int q = blockIdx.x >> 9;   // code quarter
  const int row0 = rb * 64 + w * 16;
  const int c0 = q * 256;
  const int ln = lane & 15;
  const int kb = lane >> 4;

  f32x4v acc[16];
  #pragma unroll
  for (int t = 0; t < 16; ++t) acc[t] = (f32x4v){0.f, 0.f, 0.f, 0.f};

  const unsigned short* pa = rhi + (size_t)(rb * 4 + w) * 4096 + lane * 8;
  // wave w stages tiles lt = j*4+w (j=0..3); source tile = q*16 + lt
  const unsigned short* pb = chi_l + (size_t)(q * 16 + w) * 4096 + lane * 8;
  const int ldst = w * 512 + lane * 8;  // + j*2048

  // prologue: stage slice ks=0; load A for ks=0
  {
    uint4 s0 = *reinterpret_cast<const uint4*>(pb);
    uint4 s1 = *reinterpret_cast<const uint4*>(pb + 16384);
    uint4 s2 = *reinterpret_cast<const uint4*>(pb + 32768);
    uint4 s3 = *reinterpret_cast<const uint4*>(pb + 49152);
    *reinterpret_cast<uint4*>(&Blds[0][ldst])         = s0;
    *reinterpret_cast<uint4*>(&Blds[0][ldst + 2048])  = s1;
    *reinterpret_cast<uint4*>(&Blds[0][ldst + 4096])  = s2;
    *reinterpret_cast<uint4*>(&Blds[0][ldst + 6144])  = s3;
  }
  short8v a = *reinterpret_cast<const short8v*>(pa);
  __syncthreads();

  int buf = 0;
  #pragma unroll 1
  for (int ks = 0; ks < 8; ++ks) {
    uint4 st0, st1, st2, st3;
    short8v an;
    if (ks < 7) {  // issue next slice's loads before compute
      const unsigned short* pn = pb + (ks + 1) * 512;
      st0 = *reinterpret_cast<const uint4*>(pn);
      st1 = *reinterpret_cast<const uint4*>(pn + 16384);
      st2 = *reinterpret_cast<const uint4*>(pn + 32768);
      st3 = *reinterpret_cast<const uint4*>(pn + 49152);
      an = *reinterpret_cast<const short8v*>(pa + (ks + 1) * 512);
    }
    const unsigned short* bb = &Blds[buf][0];
    #pragma unroll
    for (int t = 0; t < 16; ++t) {
      short8v b = *reinterpret_cast<const short8v*>(bb + t * 512 + lane * 8);
      acc[t] = __builtin_amdgcn_mfma_f32_16x16x32_bf16(a, b, acc[t], 0, 0, 0);
    }
    if (ks < 7) {  // write-late (buf^1 free since previous barrier), 1 barrier
      unsigned short* bd = &Blds[buf ^ 1][0];
      *reinterpret_cast<uint4*>(&bd[ldst])        = st0;
      *reinterpret_cast<uint4*>(&bd[ldst + 2048]) = st1;
      *reinterpret_cast<uint4*>(&bd[ldst + 4096]) = st2;
      *reinterpret_cast<uint4*>(&bd[ldst + 6144]) = st3;
      a = an;
      __syncthreads();
      buf ^= 1;
    }
  }

  // per-row (kb*4+g) min over this quarter; emit survivors vs local min+MARGIN
  float bvl[16];
  #pragma unroll
  for (int t = 0; t < 16; ++t) bvl[t] = bv_l[c0 + t * 16 + ln];
  float rq[4];
  #pragma unroll
  for (int g = 0; g < 4; ++g) rq[g] = rowsq[row0 + kb * 4 + g];

  float thr[4];
  #pragma unroll
  for (int g = 0; g < 4; ++g) {
    float v = __builtin_inff();
    #pragma unroll
    for (int t = 0; t < 16; ++t) {
      float dd = (rq[g] + bvl[t]) - 2.0f * acc[t][g];
      v = fminf(v, dd);
    }
    #pragma unroll
    for (int m = 1; m < 16; m <<= 1) v = fminf(v, __shfl_xor(v, m));
    thr[g] = v + MARGIN;
  }
  #pragma unroll
  for (int g = 0; g < 4; ++g) {
    const int row = row0 + kb * 4 + g;
    #pragma unroll
    for (int t = 0; t < 16; ++t) {
      float dd = (rq[g] + bvl[t]) - 2.0f * acc[t][g];
      if (dd <= thr[g]) {
        unsigned slot = atomicAdd(&counts_l[row], 1u);
        if (slot < CAP)
          survq[(size_t)row * CAP + slot] = (unsigned)(c0 + t * 16 + ln);
      }
    }
  }
}

// ============ fused exact rescore + residual update (verified r14/r15) ============
__global__ __launch_bounds__(256) void k_exupd(const float* __restrict__ x,
                                               const float* __restrict__ cb,
                                               const float* __restrict__ bv,
                                               const float* __restrict__ rowsq,
                                               const unsigned* __restrict__ survq,
                                               const unsigned* __restrict__ counts_l,
                                               int* __restrict__ idxh,
                                               float* __restrict__ fidx,
                                               float* __restrict__ tq,
                                               float* __restrict__ part,
                                               float* __restrict__ rowsq_o,
                                               unsigned short* __restrict__ rhi,
                                               int lvl) {
  __shared__ __align__(16) float rlds[16][260];
  __shared__ int idsh[16];
  __shared__ float sred[256];
  __shared__ float rsum[16];

  const int tid = threadIdx.x;
  const int rr = tid >> 4;
  const int l16 = tid & 15;
  const int row = blockIdx.x * 16 + rr;
  const size_t obase = (size_t)row * DIM + l16 * 16;
  const float* cb_l = cb + (size_t)lvl * KCODES * DIM;
  const float* bv_l = bv + lvl * KCODES;

  // ---- phase A: residual via verified fl chain; stage row in LDS ----
  float4 xj[4], rj[4];
  {
    const float4* xp = reinterpret_cast<const float4*>(x + obase);
    #pragma unroll
    for (int j = 0; j < 4; ++j) { xj[j] = xp[j]; rj[j] = xj[j]; }
    for (int p = 0; p < lvl; ++p) {
      const float4* qp = reinterpret_cast<const float4*>(
          cb + ((size_t)p * KCODES + idxh[p * NROWS + row]) * DIM + l16 * 16);
      #pragma unroll
      for (int j = 0; j < 4; ++j) {
        float4 q = qp[j];
        rj[j].x -= q.x; rj[j].y -= q.y; rj[j].z -= q.z; rj[j].w -= q.w;
      }
    }
    #pragma unroll
    for (int j = 0; j < 4; ++j)
      *reinterpret_cast<float4*>(&rlds[rr][l16 * 16 + 4 * j]) = rj[j];
  }
  __syncthreads();

  // ---- phase B: exact chains on survivors ----
  const float A = rowsq[row];
  const unsigned n = counts_l[row];
  unsigned long long best = ~0ull;

#define CHAIN(CODE)                                                            \
  {                                                                            \
    const float* cp2 = cb_l + (size_t)(CODE) * DIM;                            \
    float a0 = 0.f;                                                            \
    _Pragma("unroll 8")                                                        \
    for (int dv = 0; dv < DIM / 4; ++dv) {                                     \
      float4 rv = *reinterpret_cast<const float4*>(&rlds[rr][dv * 4]);         \
      float4 cv = *reinterpret_cast<const float4*>(cp2 + dv * 4);              \
      a0 = fmaf(rv.x, cv.x, a0); a0 = fmaf(rv.y, cv.y, a0);                    \
      a0 = fmaf(rv.z, cv.z, a0); a0 = fmaf(rv.w, cv.w, a0);                    \
    }                                                                          \
    float t = A + bv_l[(CODE)];   /* fl(A + B) */                              \
    float dd = t - 2.0f * a0;     /* one rounding (2*dot exact) */             \
    unsigned long long pk =                                                    \
        ((unsigned long long)__float_as_uint(dd) << 32) | (unsigned)(CODE);    \
    best = (pk < best) ? pk : best;                                            \
  }

  if (n <= CAP) {
    for (unsigned s = l16; s < n; s += 16) {
      unsigned code = survq[(size_t)row * CAP + s];
      CHAIN(code);
    }
  } else {
    for (unsigned c = l16; c < KCODES; c += 16) CHAIN(c);  // safety net
  }
#undef CHAIN

  #pragma unroll
  for (int m = 1; m < 16; m <<= 1) {
    unsigned long long o = __shfl_xor(best, m);
    best = (o < best) ? o : best;
  }
  if (l16 == 0) {
    const int id = (int)(best & 0xffffffffull);
    idxh[lvl * NROWS + row] = id;
    fidx[lvl * NROWS + row] = (float)id;
    idsh[rr] = id;
  }
  __syncthreads();

  // ---- phase C: verified k_update math inline ----
  const int id = idsh[rr];
  const float4* cpc = reinterpret_cast<const float4*>(
      cb_l + (size_t)id * DIM + l16 * 16);
  float4* tp = reinterpret_cast<float4*>(tq + obase);
  float nn[16];
  float e = 0.f;
  #pragma unroll
  for (int j = 0; j < 4; ++j) {
    float4 c = cpc[j];
    float n0 = rj[j].x - c.x, n1 = rj[j].y - c.y;
    float n2 = rj[j].z - c.z, n3 = rj[j].w - c.w;
    nn[4 * j + 0] = n0; nn[4 * j + 1] = n1; nn[4 * j + 2] = n2; nn[4 * j + 3] = n3;
    e += (n0 * n0 + n1 * n1) + (n2 * n2 + n3 * n3);
    float4 tv;
    if (lvl == 0) {
      tv = c;
    } else {
      tv = tp[j];
      tv.x += c.x; tv.y += c.y; tv.z += c.z; tv.w += c.w;
    }
    if (lvl == 3) {
      tv.x = xj[j].x + (tv.x - xj[j].x); tv.y = xj[j].y + (tv.y - xj[j].y);
      tv.z = xj[j].z + (tv.z - xj[j].z); tv.w = xj[j].w + (tv.w - xj[j].w);
    }
    tp[j] = tv;
  }

  if (lvl < 3) {
    unsigned w[8];
    #pragma unroll
    for (int k = 0; k < 8; ++k)
      w[k] = (unsigned)f2bf(nn[2 * k]) | ((unsigned)f2bf(nn[2 * k + 1]) << 16);
    unsigned short* base = rhi + (size_t)blockIdx.x * 4096;
    const int ks = l16 >> 1;
    const int kb0 = (l16 & 1) * 2;
    *reinterpret_cast<uint4*>(base + ks * 512 + kb0 * 128 + rr * 8) =
        make_uint4(w[0], w[1], w[2], w[3]);
    *reinterpret_cast<uint4*>(base + ks * 512 + (kb0 + 1) * 128 + rr * 8) =
        make_uint4(w[4], w[5], w[6], w[7]);
  }

  sred[tid] = e;
  __syncthreads();
  if (tid < 16) {
    float s = 0.f;
    #pragma unroll
    for (int k = 0; k < 16; ++k) s += sred[tid * 16 + k];
    rsum[tid] = s;
    if (lvl < 3) rowsq_o[blockIdx.x * 16 + tid] = s;
  }
  __syncthreads();
  if (tid == 0) {
    float p = 0.f;
    #pragma unroll
    for (int k = 0; k < 16; ++k) p += rsum[k];
    part[blockIdx.x] = p;
  }
}

// ============ loss finalize (unchanged) ============
__global__ __launch_bounds__(256) void k_loss(const float* __restrict__ part,
                                              float* __restrict__ out) {
  __shared__ float s[256];
  const int tid = threadIdx.x;
  float means[4];
  for (int l = 0; l < 4; ++l) {
    float sum = 0.f;
    for (int i = tid; i < 2048; i += 256) sum += part[l * 2048 + i];
    s[tid] = sum;
    __syncthreads();
    for (int st = 128; st > 0; st >>= 1) {
      if (tid < st) s[tid] += s[tid + st];
      __syncthreads();
    }
    means[l] = s[0] * (1.0f / 8388608.0f);
    __syncthreads();
  }
  if (tid == 0) {
    float t = ((means[0] + means[1]) + means[2]) + means[3];
    float loss = t * 0.25f;
    out[0] = loss;
    out[1] = loss;
  }
}

extern "C" void kernel_launch(void* const* d_in, const int* in_sizes, int n_in,
                              void* d_out, int out_size, void* d_ws, size_t ws_size,
                              hipStream_t stream) {
  const float* x  = (const float*)d_in[0];
  const float* cb = (const float*)d_in[1];
  float* out = (float*)d_out;
  float* ws  = (float*)d_ws;

  // ws layout (float units)
  unsigned short* rhi = (unsigned short*)ws;                         // 4194304 f
  unsigned short* chi = (unsigned short*)(ws + 4194304);             // 524288 f
  unsigned* survq   = (unsigned*)(ws + 4194304 + 524288);            // 2097152 f
  unsigned* counts4 = (unsigned*)(ws + 4194304 + 524288 + 2097152);  // 131072 f (4 levels)
  int* idxh = (int*)(ws + 4194304 + 524288 + 2097152 + 131072);      // 131072 f
  float* bv    = ws + 4194304 + 524288 + 2097152 + 131072 + 131072;  // 4096
  float* rowsq = bv + 4096;                                          // 32768
  float* part  = rowsq + 32768;                                      // 8192

  float* tq      = out;                    // total_quant accumulates in d_out
  float* lossout = out + 8388608;
  float* fidx    = out + 8388610;

  hipMemsetAsync(counts4, 0, (size_t)NLEV * NROWS * sizeof(unsigned), stream);
  k_bnorm<<<16, 256, 0, stream>>>(cb, bv);
  k_csplit<<<256, 256, 0, stream>>>(cb, chi);
  k_prep<<<2048, 256, 0, stream>>>(x, rhi, rowsq);

  for (int l = 0; l < NLEV; ++l) {
    unsigned* counts_l = counts4 + (size_t)l * NROWS;
    k_screen<<<2048, 256, 0, stream>>>(rhi, chi + (size_t)l * KCODES * DIM,
                                       bv + l * KCODES, rowsq, survq, counts_l);
    k_exupd<<<2048, 256, 0, stream>>>(x, cb, bv, rowsq, survq, counts_l,
                                      idxh, fidx, tq, part + l * 2048,
                                      rowsq, rhi, l);
  }

  k_loss<<<1, 256, 0, stream>>>(part, lossout);
}

// Round 19
// 738.113 us; speedup vs baseline: 1.0411x; 1.0411x over previous
//
#include <hip/hip_runtime.h>

#define NROWS 32768   // B*T = 16*2048
#define DIM 256
#define KCODES 1024
#define NLEV 4
#define CAP 64
#define MARGIN 8e-3f

typedef short short8v __attribute__((ext_vector_type(8)));
typedef float f32x4v  __attribute__((ext_vector_type(4)));

// bf16 round-to-nearest-even
static __device__ __forceinline__ unsigned short f2bf(float f) {
  unsigned u = __float_as_uint(f);
  unsigned lsb = (u >> 16) & 1u;
  u += 0x7fffu + lsb;
  return (unsigned short)(u >> 16);
}

// async global->LDS, 16B per lane: per-lane global src, wave-uniform LDS dest
static __device__ __forceinline__ void gll16(const unsigned short* g,
                                             unsigned short* l) {
  __builtin_amdgcn_global_load_lds(
      (const __attribute__((address_space(1))) unsigned int*)g,
      (__attribute__((address_space(3))) unsigned int*)l, 16, 0, 0);
}

// Packed fragment layout (per 16-row/16-code tile of 256 dims = 4096 shorts):
//   pak[tile][ks*512 + kb*128 + r8*8 + j] = elem(row = tile*16 + r8,
//                                               k = ks*32 + kb*8 + j)
// Wave reads short8v at pak + tile*4096 + ks*512 + lane*8 -> contiguous 1 KB.

// ============ codebook squared norms (unchanged, verified) ============
__global__ __launch_bounds__(256) void k_bnorm(const float* __restrict__ cb,
                                               float* __restrict__ bv) {
  int r = blockIdx.x * blockDim.x + threadIdx.x;
  if (r >= NLEV * KCODES) return;
  const float4* p = reinterpret_cast<const float4*>(cb + (size_t)r * DIM);
  float s0 = 0.f, s1 = 0.f, s2 = 0.f, s3 = 0.f;
  for (int g = 0; g < DIM / 4; ++g) {
    float4 v = p[g];
    s0 += v.x * v.x; s1 += v.y * v.y; s2 += v.z * v.z; s3 += v.w * v.w;
  }
  bv[r] = (s0 + s1) + (s2 + s3);
}

// ============ codebook -> bf16, PACKED fragment layout (verified r15) ============
__global__ __launch_bounds__(256) void k_csplit(const float* __restrict__ cb,
                                                unsigned short* __restrict__ chi) {
  const int tid = threadIdx.x;
  const int cr = blockIdx.x * 16 + (tid >> 4);
  const int l16 = tid & 15;
  const float4* p = reinterpret_cast<const float4*>(cb + (size_t)cr * DIM + l16 * 16);
  unsigned w[8];
  #pragma unroll
  for (int j = 0; j < 4; ++j) {
    float4 v = p[j];
    w[2 * j + 0] = (unsigned)f2bf(v.x) | ((unsigned)f2bf(v.y) << 16);
    w[2 * j + 1] = (unsigned)f2bf(v.z) | ((unsigned)f2bf(v.w) << 16);
  }
  const int lvl_ = cr >> 10;
  const int c = cr & 1023;
  unsigned short* base = chi + (size_t)lvl_ * (KCODES * DIM) + (size_t)(c >> 4) * 4096;
  const int c8 = c & 15;
  const int ks = l16 >> 1;
  const int kb0 = (l16 & 1) * 2;
  *reinterpret_cast<uint4*>(base + ks * 512 + kb0 * 128 + c8 * 8) =
      make_uint4(w[0], w[1], w[2], w[3]);
  *reinterpret_cast<uint4*>(base + ks * 512 + (kb0 + 1) * 128 + c8 * 8) =
      make_uint4(w[4], w[5], w[6], w[7]);
}

// ============ x -> rowsq + rhi (PACKED, verified r15) ============
__global__ __launch_bounds__(256) void k_prep(const float* __restrict__ x,
                                              unsigned short* __restrict__ rhi,
                                              float* __restrict__ rowsq) {
  __shared__ float sred[256];
  const int tid = threadIdx.x;
  const int rr = tid >> 4;
  const int l16 = tid & 15;
  const int row = blockIdx.x * 16 + rr;
  const float4* p = reinterpret_cast<const float4*>(x + (size_t)row * DIM + l16 * 16);
  float e = 0.f;
  unsigned w[8];
  #pragma unroll
  for (int j = 0; j < 4; ++j) {
    float4 v = p[j];
    e += v.x * v.x + v.y * v.y + v.z * v.z + v.w * v.w;
    w[2 * j + 0] = (unsigned)f2bf(v.x) | ((unsigned)f2bf(v.y) << 16);
    w[2 * j + 1] = (unsigned)f2bf(v.z) | ((unsigned)f2bf(v.w) << 16);
  }
  unsigned short* base = rhi + (size_t)blockIdx.x * 4096;
  const int ks = l16 >> 1;
  const int kb0 = (l16 & 1) * 2;
  *reinterpret_cast<uint4*>(base + ks * 512 + kb0 * 128 + rr * 8) =
      make_uint4(w[0], w[1], w[2], w[3]);
  *reinterpret_cast<uint4*>(base + ks * 512 + (kb0 + 1) * 128 + rr * 8) =
      make_uint4(w[4], w[5], w[6], w[7]);
  sred[tid] = e;
  __syncthreads();
  if (tid < 16) {
    float s = 0.f;
    #pragma unroll
    for (int k = 0; k < 16; ++k) s += sred[tid * 16 + k];
    rowsq[blockIdx.x * 16 + tid] = s;
  }
}

// ============ MFMA bf16 screen: async LDS staging (m97 schedule) ============
// 2048 blocks = 512 row-blocks x 4 code-quarters (r18 geometry, verified).
// Per ks-step: each wave fire-and-forgets 4x global_load_lds(16B/lane) for
// slice ks+1 into buf^1 (zero VGPR staging -> no spills), computes slice ks
// from buf (16 ds_read_b128 + 16 MFMA), then one __syncthreads (drains vmcnt
// -> writes landed; double-buffer hazard-free). acc[16]=64 AGPR, ~40 VGPR ->
// 4-5 blocks/CU TLP. Survivors vs quarter-local min + MARGIN (r16/r18-
// validated), global atomic slots. Fragments bit-identical to r12-r18.
__global__ __launch_bounds__(256) void k_screen(const unsigned short* __restrict__ rhi,
                                                const unsigned short* __restrict__ chi_l,
                                                const float* __restrict__ bv_l,
                                                const float* __restrict__ rowsq,
                                                unsigned* __restrict__ survq,
                                                unsigned* __restrict__ counts_l) {
  __shared__ __align__(16) unsigned short Blds[2][8192];  // 2 x 16 KB
  const int tid = threadIdx.x;
  const int lane = tid & 63;
  const int w = tid >> 6;          // wave = row-tile 0..3
  const int rb = blockIdx.x & 511; // row block (64 rows)
  const int q = blockIdx.x >> 9;   // code quarter
  const int row0 = rb * 64 + w * 16;
  const int c0 = q * 256;
  const int ln = lane & 15;
  const int kb = lane >> 4;

  f32x4v acc[16];
  #pragma unroll
  for (int t = 0; t < 16; ++t) acc[t] = (f32x4v){0.f, 0.f, 0.f, 0.f};

  const unsigned short* pa = rhi + (size_t)(rb * 4 + w) * 4096 + lane * 8;
  // wave w stages LDS slots {w, w+4, w+8, w+12} from source tiles q*16 + slot
  const unsigned short* pb = chi_l + (size_t)(q * 16 + w) * 4096 + lane * 8;

  // prologue: async-stage slice 0 into buf 0; A for ks=0 in regs
  {
    #pragma unroll
    for (int j = 0; j < 4; ++j)
      gll16(pb + j * 16384, &Blds[0][(w + 4 * j) * 512]);
  }
  short8v a = *reinterpret_cast<const short8v*>(pa);
  __syncthreads();  // drains vmcnt -> slice 0 in LDS

  int buf = 0;
  #pragma unroll 1
  for (int ks = 0; ks < 8; ++ks) {
    short8v an;
    if (ks < 7) {  // fire-and-forget next slice into buf^1 BEFORE compute
      const unsigned short* pn = pb + (ks + 1) * 512;
      #pragma unroll
      for (int j = 0; j < 4; ++j)
        gll16(pn + j * 16384, &Blds[buf ^ 1][(w + 4 * j) * 512]);
      an = *reinterpret_cast<const short8v*>(pa + (ks + 1) * 512);
    }
    const unsigned short* bb = &Blds[buf][0];
    #pragma unroll
    for (int t = 0; t < 16; ++t) {
      short8v b = *reinterpret_cast<const short8v*>(bb + t * 512 + lane * 8);
      acc[t] = __builtin_amdgcn_mfma_f32_16x16x32_bf16(a, b, acc[t], 0, 0, 0);
    }
    if (ks < 7) {
      a = an;
      __syncthreads();  // vmcnt drained -> slice ks+1 landed; readers synced
      buf ^= 1;
    }
  }

  // per-row min over this quarter; emit survivors vs local min + MARGIN
  float bvl[16];
  #pragma unroll
  for (int t = 0; t < 16; ++t) bvl[t] = bv_l[c0 + t * 16 + ln];
  float rq[4];
  #pragma unroll
  for (int g = 0; g < 4; ++g) rq[g] = rowsq[row0 + kb * 4 + g];

  float thr[4];
  #pragma unroll
  for (int g = 0; g < 4; ++g) {
    float v = __builtin_inff();
    #pragma unroll
    for (int t = 0; t < 16; ++t) {
      float dd = (rq[g] + bvl[t]) - 2.0f * acc[t][g];
      v = fminf(v, dd);
    }
    #pragma unroll
    for (int m = 1; m < 16; m <<= 1) v = fminf(v, __shfl_xor(v, m));
    thr[g] = v + MARGIN;
  }
  #pragma unroll
  for (int g = 0; g < 4; ++g) {
    const int row = row0 + kb * 4 + g;
    #pragma unroll
    for (int t = 0; t < 16; ++t) {
      float dd = (rq[g] + bvl[t]) - 2.0f * acc[t][g];
      if (dd <= thr[g]) {
        unsigned slot = atomicAdd(&counts_l[row], 1u);
        if (slot < CAP)
          survq[(size_t)row * CAP + slot] = (unsigned)(c0 + t * 16 + ln);
      }
    }
  }
}

// ============ fused exact rescore + residual update (verified r14/r15/r18) ============
__global__ __launch_bounds__(256) void k_exupd(const float* __restrict__ x,
                                               const float* __restrict__ cb,
                                               const float* __restrict__ bv,
                                               const float* __restrict__ rowsq,
                                               const unsigned* __restrict__ survq,
                                               const unsigned* __restrict__ counts_l,
                                               int* __restrict__ idxh,
                                               float* __restrict__ fidx,
                                               float* __restrict__ tq,
                                               float* __restrict__ part,
                                               float* __restrict__ rowsq_o,
                                               unsigned short* __restrict__ rhi,
                                               int lvl) {
  __shared__ __align__(16) float rlds[16][260];
  __shared__ int idsh[16];
  __shared__ float sred[256];
  __shared__ float rsum[16];

  const int tid = threadIdx.x;
  const int rr = tid >> 4;
  const int l16 = tid & 15;
  const int row = blockIdx.x * 16 + rr;
  const size_t obase = (size_t)row * DIM + l16 * 16;
  const float* cb_l = cb + (size_t)lvl * KCODES * DIM;
  const float* bv_l = bv + lvl * KCODES;

  // ---- phase A: residual via verified fl chain; stage row in LDS ----
  float4 xj[4], rj[4];
  {
    const float4* xp = reinterpret_cast<const float4*>(x + obase);
    #pragma unroll
    for (int j = 0; j < 4; ++j) { xj[j] = xp[j]; rj[j] = xj[j]; }
    for (int p = 0; p < lvl; ++p) {
      const float4* qp = reinterpret_cast<const float4*>(
          cb + ((size_t)p * KCODES + idxh[p * NROWS + row]) * DIM + l16 * 16);
      #pragma unroll
      for (int j = 0; j < 4; ++j) {
        float4 q = qp[j];
        rj[j].x -= q.x; rj[j].y -= q.y; rj[j].z -= q.z; rj[j].w -= q.w;
      }
    }
    #pragma unroll
    for (int j = 0; j < 4; ++j)
      *reinterpret_cast<float4*>(&rlds[rr][l16 * 16 + 4 * j]) = rj[j];
  }
  __syncthreads();

  // ---- phase B: exact chains on survivors ----
  const float A = rowsq[row];
  const unsigned n = counts_l[row];
  unsigned long long best = ~0ull;

#define CHAIN(CODE)                                                            \
  {                                                                            \
    const float* cp2 = cb_l + (size_t)(CODE) * DIM;                            \
    float a0 = 0.f;                                                            \
    _Pragma("unroll 8")                                                        \
    for (int dv = 0; dv < DIM / 4; ++dv) {                                     \
      float4 rv = *reinterpret_cast<const float4*>(&rlds[rr][dv * 4]);         \
      float4 cv = *reinterpret_cast<const float4*>(cp2 + dv * 4);              \
      a0 = fmaf(rv.x, cv.x, a0); a0 = fmaf(rv.y, cv.y, a0);                    \
      a0 = fmaf(rv.z, cv.z, a0); a0 = fmaf(rv.w, cv.w, a0);                    \
    }                                                                          \
    float t = A + bv_l[(CODE)];   /* fl(A + B) */                              \
    float dd = t - 2.0f * a0;     /* one rounding (2*dot exact) */             \
    unsigned long long pk =                                                    \
        ((unsigned long long)__float_as_uint(dd) << 32) | (unsigned)(CODE);    \
    best = (pk < best) ? pk : best;                                            \
  }

  if (n <= CAP) {
    for (unsigned s = l16; s < n; s += 16) {
      unsigned code = survq[(size_t)row * CAP + s];
      CHAIN(code);
    }
  } else {
    for (unsigned c = l16; c < KCODES; c += 16) CHAIN(c);  // safety net
  }
#undef CHAIN

  #pragma unroll
  for (int m = 1; m < 16; m <<= 1) {
    unsigned long long o = __shfl_xor(best, m);
    best = (o < best) ? o : best;
  }
  if (l16 == 0) {
    const int id = (int)(best & 0xffffffffull);
    idxh[lvl * NROWS + row] = id;
    fidx[lvl * NROWS + row] = (float)id;
    idsh[rr] = id;
  }
  __syncthreads();

  // ---- phase C: verified k_update math inline ----
  const int id = idsh[rr];
  const float4* cpc = reinterpret_cast<const float4*>(
      cb_l + (size_t)id * DIM + l16 * 16);
  float4* tp = reinterpret_cast<float4*>(tq + obase);
  float nn[16];
  float e = 0.f;
  #pragma unroll
  for (int j = 0; j < 4; ++j) {
    float4 c = cpc[j];
    float n0 = rj[j].x - c.x, n1 = rj[j].y - c.y;
    float n2 = rj[j].z - c.z, n3 = rj[j].w - c.w;
    nn[4 * j + 0] = n0; nn[4 * j + 1] = n1; nn[4 * j + 2] = n2; nn[4 * j + 3] = n3;
    e += (n0 * n0 + n1 * n1) + (n2 * n2 + n3 * n3);
    float4 tv;
    if (lvl == 0) {
      tv = c;
    } else {
      tv = tp[j];
      tv.x += c.x; tv.y += c.y; tv.z += c.z; tv.w += c.w;
    }
    if (lvl == 3) {
      tv.x = xj[j].x + (tv.x - xj[j].x); tv.y = xj[j].y + (tv.y - xj[j].y);
      tv.z = xj[j].z + (tv.z - xj[j].z); tv.w = xj[j].w + (tv.w - xj[j].w);
    }
    tp[j] = tv;
  }

  if (lvl < 3) {
    unsigned w[8];
    #pragma unroll
    for (int k = 0; k < 8; ++k)
      w[k] = (unsigned)f2bf(nn[2 * k]) | ((unsigned)f2bf(nn[2 * k + 1]) << 16);
    unsigned short* base = rhi + (size_t)blockIdx.x * 4096;
    const int ks = l16 >> 1;
    const int kb0 = (l16 & 1) * 2;
    *reinterpret_cast<uint4*>(base + ks * 512 + kb0 * 128 + rr * 8) =
        make_uint4(w[0], w[1], w[2], w[3]);
    *reinterpret_cast<uint4*>(base + ks * 512 + (kb0 + 1) * 128 + rr * 8) =
        make_uint4(w[4], w[5], w[6], w[7]);
  }

  sred[tid] = e;
  __syncthreads();
  if (tid < 16) {
    float s = 0.f;
    #pragma unroll
    for (int k = 0; k < 16; ++k) s += sred[tid * 16 + k];
    rsum[tid] = s;
    if (lvl < 3) rowsq_o[blockIdx.x * 16 + tid] = s;
  }
  __syncthreads();
  if (tid == 0) {
    float p = 0.f;
    #pragma unroll
    for (int k = 0; k < 16; ++k) p += rsum[k];
    part[blockIdx.x] = p;
  }
}

// ============ loss finalize (unchanged) ============
__global__ __launch_bounds__(256) void k_loss(const float* __restrict__ part,
                                              float* __restrict__ out) {
  __shared__ float s[256];
  const int tid = threadIdx.x;
  float means[4];
  for (int l = 0; l < 4; ++l) {
    float sum = 0.f;
    for (int i = tid; i < 2048; i += 256) sum += part[l * 2048 + i];
    s[tid] = sum;
    __syncthreads();
    for (int st = 128; st > 0; st >>= 1) {
      if (tid < st) s[tid] += s[tid + st];
      __syncthreads();
    }
    means[l] = s[0] * (1.0f / 8388608.0f);
    __syncthreads();
  }
  if (tid == 0) {
    float t = ((means[0] + means[1]) + means[2]) + means[3];
    float loss = t * 0.25f;
    out[0] = loss;
    out[1] = loss;
  }
}

extern "C" void kernel_launch(void* const* d_in, const int* in_sizes, int n_in,
                              void* d_out, int out_size, void* d_ws, size_t ws_size,
                              hipStream_t stream) {
  const float* x  = (const float*)d_in[0];
  const float* cb = (const float*)d_in[1];
  float* out = (float*)d_out;
  float* ws  = (float*)d_ws;

  // ws layout (float units)
  unsigned short* rhi = (unsigned short*)ws;                         // 4194304 f
  unsigned short* chi = (unsigned short*)(ws + 4194304);             // 524288 f
  unsigned* survq   = (unsigned*)(ws + 4194304 + 524288);            // 2097152 f
  unsigned* counts4 = (unsigned*)(ws + 4194304 + 524288 + 2097152);  // 131072 f (4 levels)
  int* idxh = (int*)(ws + 4194304 + 524288 + 2097152 + 131072);      // 131072 f
  float* bv    = ws + 4194304 + 524288 + 2097152 + 131072 + 131072;  // 4096
  float* rowsq = bv + 4096;                                          // 32768
  float* part  = rowsq + 32768;                                      // 8192

  float* tq      = out;                    // total_quant accumulates in d_out
  float* lossout = out + 8388608;
  float* fidx    = out + 8388610;

  hipMemsetAsync(counts4, 0, (size_t)NLEV * NROWS * sizeof(unsigned), stream);
  k_bnorm<<<16, 256, 0, stream>>>(cb, bv);
  k_csplit<<<256, 256, 0, stream>>>(cb, chi);
  k_prep<<<2048, 256, 0, stream>>>(x, rhi, rowsq);

  for (int l = 0; l < NLEV; ++l) {
    unsigned* counts_l = counts4 + (size_t)l * NROWS;
    k_screen<<<2048, 256, 0, stream>>>(rhi, chi + (size_t)l * KCODES * DIM,
                                       bv + l * KCODES, rowsq, survq, counts_l);
    k_exupd<<<2048, 256, 0, stream>>>(x, cb, bv, rowsq, survq, counts_l,
                                      idxh, fidx, tq, part + l * 2048,
                                      rowsq, rhi, l);
  }

  k_loss<<<1, 256, 0, stream>>>(part, lossout);
}

// Round 20
// 426.413 us; speedup vs baseline: 1.8021x; 1.7310x over previous
//
#include <hip/hip_runtime.h>

#define NROWS 32768   // B*T = 16*2048
#define DIM 256
#define KCODES 1024
#define NLEV 4
#define CAP 64
#define MARGIN 8e-3f

typedef short short8v __attribute__((ext_vector_type(8)));
typedef float f32x4v  __attribute__((ext_vector_type(4)));

// bf16 round-to-nearest-even
static __device__ __forceinline__ unsigned short f2bf(float f) {
  unsigned u = __float_as_uint(f);
  unsigned lsb = (u >> 16) & 1u;
  u += 0x7fffu + lsb;
  return (unsigned short)(u >> 16);
}

// Packed fragment layout (per 16-row/16-code tile of 256 dims = 4096 shorts):
//   pak[tile][ks*512 + kb*128 + r8*8 + j] = elem(row = tile*16 + r8,
//                                               k = ks*32 + kb*8 + j)
// Wave reads short8v at pak + tile*4096 + ks*512 + lane*8 -> contiguous 1 KB.

// ============ codebook squared norms (unchanged, verified) ============
__global__ __launch_bounds__(256) void k_bnorm(const float* __restrict__ cb,
                                               float* __restrict__ bv) {
  int r = blockIdx.x * blockDim.x + threadIdx.x;
  if (r >= NLEV * KCODES) return;
  const float4* p = reinterpret_cast<const float4*>(cb + (size_t)r * DIM);
  float s0 = 0.f, s1 = 0.f, s2 = 0.f, s3 = 0.f;
  for (int g = 0; g < DIM / 4; ++g) {
    float4 v = p[g];
    s0 += v.x * v.x; s1 += v.y * v.y; s2 += v.z * v.z; s3 += v.w * v.w;
  }
  bv[r] = (s0 + s1) + (s2 + s3);
}

// ============ codebook -> bf16, PACKED fragment layout (verified r15) ============
__global__ __launch_bounds__(256) void k_csplit(const float* __restrict__ cb,
                                                unsigned short* __restrict__ chi) {
  const int tid = threadIdx.x;
  const int cr = blockIdx.x * 16 + (tid >> 4);
  const int l16 = tid & 15;
  const float4* p = reinterpret_cast<const float4*>(cb + (size_t)cr * DIM + l16 * 16);
  unsigned w[8];
  #pragma unroll
  for (int j = 0; j < 4; ++j) {
    float4 v = p[j];
    w[2 * j + 0] = (unsigned)f2bf(v.x) | ((unsigned)f2bf(v.y) << 16);
    w[2 * j + 1] = (unsigned)f2bf(v.z) | ((unsigned)f2bf(v.w) << 16);
  }
  const int lvl_ = cr >> 10;
  const int c = cr & 1023;
  unsigned short* base = chi + (size_t)lvl_ * (KCODES * DIM) + (size_t)(c >> 4) * 4096;
  const int c8 = c & 15;
  const int ks = l16 >> 1;
  const int kb0 = (l16 & 1) * 2;
  *reinterpret_cast<uint4*>(base + ks * 512 + kb0 * 128 + c8 * 8) =
      make_uint4(w[0], w[1], w[2], w[3]);
  *reinterpret_cast<uint4*>(base + ks * 512 + (kb0 + 1) * 128 + c8 * 8) =
      make_uint4(w[4], w[5], w[6], w[7]);
}

// ============ x -> rowsq + rhi (PACKED, verified r15) ============
__global__ __launch_bounds__(256) void k_prep(const float* __restrict__ x,
                                              unsigned short* __restrict__ rhi,
                                              float* __restrict__ rowsq) {
  __shared__ float sred[256];
  const int tid = threadIdx.x;
  const int rr = tid >> 4;
  const int l16 = tid & 15;
  const int row = blockIdx.x * 16 + rr;
  const float4* p = reinterpret_cast<const float4*>(x + (size_t)row * DIM + l16 * 16);
  float e = 0.f;
  unsigned w[8];
  #pragma unroll
  for (int j = 0; j < 4; ++j) {
    float4 v = p[j];
    e += v.x * v.x + v.y * v.y + v.z * v.z + v.w * v.w;
    w[2 * j + 0] = (unsigned)f2bf(v.x) | ((unsigned)f2bf(v.y) << 16);
    w[2 * j + 1] = (unsigned)f2bf(v.z) | ((unsigned)f2bf(v.w) << 16);
  }
  unsigned short* base = rhi + (size_t)blockIdx.x * 4096;
  const int ks = l16 >> 1;
  const int kb0 = (l16 & 1) * 2;
  *reinterpret_cast<uint4*>(base + ks * 512 + kb0 * 128 + rr * 8) =
      make_uint4(w[0], w[1], w[2], w[3]);
  *reinterpret_cast<uint4*>(base + ks * 512 + (kb0 + 1) * 128 + rr * 8) =
      make_uint4(w[4], w[5], w[6], w[7]);
  sred[tid] = e;
  __syncthreads();
  if (tid < 16) {
    float s = 0.f;
    #pragma unroll
    for (int k = 0; k < 16; ++k) s += sred[tid * 16 + k];
    rowsq[blockIdx.x * 16 + tid] = s;
  }
}

// ============ MFMA bf16 screen: batched-load schedule, full panel/block ============
// 1024 blocks x 512 thr (8 waves). Block = 32 rows x 1024 codes; wave = the
// block's 2 row-tiles x 8 code-tiles (codes w*128..w*128+127). acc[2][8] =
// 64 AGPR + 8 B-frags (32 V) + 2 A-frags; launch_bounds(512,4) -> 2 blocks/CU.
// Per ks-step: issue all 10 loads as one pack, sched_barrier(0), then 16 MFMA
// (rule #18: the fence stops the per-tile load->wait->MFMA interleave that
// serialized r14-r19; next step's loads may hoist over this step's MFMAs).
// Full-panel coverage -> block-local row min IS the global screen min (r15
// semantics, lean survivors). Fragments bit-identical to r12-r19.
__global__ __launch_bounds__(512, 4) void k_screen(const unsigned short* __restrict__ rhi,
                                                   const unsigned short* __restrict__ chi_l,
                                                   const float* __restrict__ bv_l,
                                                   const float* __restrict__ rowsq,
                                                   unsigned* __restrict__ survq,
                                                   unsigned* __restrict__ counts) {
  __shared__ float minb[32][8];
  __shared__ float rowminf[32];
  __shared__ unsigned cnt[32];
  const int tid = threadIdx.x;
  const int lane = tid & 63;
  const int w = tid >> 6;          // wave 0..7 -> codes w*128..+127
  const int rb = blockIdx.x;       // 32-row block
  const int row0 = rb * 32;
  const int c0 = w * 128;
  const int ln = lane & 15;
  const int kb = lane >> 4;

  f32x4v acc[2][8];
  #pragma unroll
  for (int r = 0; r < 2; ++r)
    #pragma unroll
    for (int t = 0; t < 8; ++t) acc[r][t] = (f32x4v){0.f, 0.f, 0.f, 0.f};

  const unsigned short* pa = rhi + (size_t)(rb * 2) * 4096 + lane * 8;
  const unsigned short* pb = chi_l + (size_t)(w * 8) * 4096 + lane * 8;

  #pragma unroll
  for (int ks = 0; ks < 8; ++ks) {
    // ---- load pack: 2 A + 8 B fragments, all independent ----
    short8v a0 = *reinterpret_cast<const short8v*>(pa + ks * 512);
    short8v a1 = *reinterpret_cast<const short8v*>(pa + 4096 + ks * 512);
    short8v b0 = *reinterpret_cast<const short8v*>(pb + 0 * 4096 + ks * 512);
    short8v b1 = *reinterpret_cast<const short8v*>(pb + 1 * 4096 + ks * 512);
    short8v b2 = *reinterpret_cast<const short8v*>(pb + 2 * 4096 + ks * 512);
    short8v b3 = *reinterpret_cast<const short8v*>(pb + 3 * 4096 + ks * 512);
    short8v b4 = *reinterpret_cast<const short8v*>(pb + 4 * 4096 + ks * 512);
    short8v b5 = *reinterpret_cast<const short8v*>(pb + 5 * 4096 + ks * 512);
    short8v b6 = *reinterpret_cast<const short8v*>(pb + 6 * 4096 + ks * 512);
    short8v b7 = *reinterpret_cast<const short8v*>(pb + 7 * 4096 + ks * 512);
    __builtin_amdgcn_sched_barrier(0);  // loads above, MFMAs below
    acc[0][0] = __builtin_amdgcn_mfma_f32_16x16x32_bf16(a0, b0, acc[0][0], 0, 0, 0);
    acc[1][0] = __builtin_amdgcn_mfma_f32_16x16x32_bf16(a1, b0, acc[1][0], 0, 0, 0);
    acc[0][1] = __builtin_amdgcn_mfma_f32_16x16x32_bf16(a0, b1, acc[0][1], 0, 0, 0);
    acc[1][1] = __builtin_amdgcn_mfma_f32_16x16x32_bf16(a1, b1, acc[1][1], 0, 0, 0);
    acc[0][2] = __builtin_amdgcn_mfma_f32_16x16x32_bf16(a0, b2, acc[0][2], 0, 0, 0);
    acc[1][2] = __builtin_amdgcn_mfma_f32_16x16x32_bf16(a1, b2, acc[1][2], 0, 0, 0);
    acc[0][3] = __builtin_amdgcn_mfma_f32_16x16x32_bf16(a0, b3, acc[0][3], 0, 0, 0);
    acc[1][3] = __builtin_amdgcn_mfma_f32_16x16x32_bf16(a1, b3, acc[1][3], 0, 0, 0);
    acc[0][4] = __builtin_amdgcn_mfma_f32_16x16x32_bf16(a0, b4, acc[0][4], 0, 0, 0);
    acc[1][4] = __builtin_amdgcn_mfma_f32_16x16x32_bf16(a1, b4, acc[1][4], 0, 0, 0);
    acc[0][5] = __builtin_amdgcn_mfma_f32_16x16x32_bf16(a0, b5, acc[0][5], 0, 0, 0);
    acc[1][5] = __builtin_amdgcn_mfma_f32_16x16x32_bf16(a1, b5, acc[1][5], 0, 0, 0);
    acc[0][6] = __builtin_amdgcn_mfma_f32_16x16x32_bf16(a0, b6, acc[0][6], 0, 0, 0);
    acc[1][6] = __builtin_amdgcn_mfma_f32_16x16x32_bf16(a1, b6, acc[1][6], 0, 0, 0);
    acc[0][7] = __builtin_amdgcn_mfma_f32_16x16x32_bf16(a0, b7, acc[0][7], 0, 0, 0);
    acc[1][7] = __builtin_amdgcn_mfma_f32_16x16x32_bf16(a1, b7, acc[1][7], 0, 0, 0);
  }

  // per-row partial min over this wave's 128 codes
  float bvl[8];
  #pragma unroll
  for (int t = 0; t < 8; ++t) bvl[t] = bv_l[c0 + t * 16 + ln];
  float rq[2][4];
  #pragma unroll
  for (int r = 0; r < 2; ++r)
    #pragma unroll
    for (int g = 0; g < 4; ++g) rq[r][g] = rowsq[row0 + r * 16 + kb * 4 + g];

  #pragma unroll
  for (int r = 0; r < 2; ++r) {
    #pragma unroll
    for (int g = 0; g < 4; ++g) {
      float v = __builtin_inff();
      #pragma unroll
      for (int t = 0; t < 8; ++t) {
        float dd = (rq[r][g] + bvl[t]) - 2.0f * acc[r][t][g];
        v = fminf(v, dd);
      }
      #pragma unroll
      for (int m = 1; m < 16; m <<= 1) v = fminf(v, __shfl_xor(v, m));
      if (ln == 0) minb[r * 16 + kb * 4 + g][w] = v;
    }
  }
  __syncthreads();
  if (tid < 32) {
    float v = minb[tid][0];
    #pragma unroll
    for (int k = 1; k < 8; ++k) v = fminf(v, minb[tid][k]);
    rowminf[tid] = v;   // TRUE screen min over all 1024 codes
    cnt[tid] = 0;
  }
  __syncthreads();
  // survivor emission vs global screen min + MARGIN (r15 semantics)
  #pragma unroll
  for (int r = 0; r < 2; ++r) {
    #pragma unroll
    for (int g = 0; g < 4; ++g) {
      const int rowloc = r * 16 + kb * 4 + g;
      const float thr = rowminf[rowloc] + MARGIN;
      #pragma unroll
      for (int t = 0; t < 8; ++t) {
        float dd = (rq[r][g] + bvl[t]) - 2.0f * acc[r][t][g];
        if (dd <= thr) {
          unsigned slot = atomicAdd(&cnt[rowloc], 1u);
          if (slot < CAP)
            survq[(size_t)(row0 + rowloc) * CAP + slot] =
                (unsigned)(c0 + t * 16 + ln);
        }
      }
    }
  }
  __syncthreads();
  if (tid < 32) counts[row0 + tid] = cnt[tid];
}

// ============ fused exact rescore + residual update (verified r14/r15) ============
__global__ __launch_bounds__(256) void k_exupd(const float* __restrict__ x,
                                               const float* __restrict__ cb,
                                               const float* __restrict__ bv,
                                               const float* __restrict__ rowsq,
                                               const unsigned* __restrict__ survq,
                                               const unsigned* __restrict__ counts,
                                               int* __restrict__ idxh,
                                               float* __restrict__ fidx,
                                               float* __restrict__ tq,
                                               float* __restrict__ part,
                                               float* __restrict__ rowsq_o,
                                               unsigned short* __restrict__ rhi,
                                               int lvl) {
  __shared__ __align__(16) float rlds[16][260];
  __shared__ int idsh[16];
  __shared__ float sred[256];
  __shared__ float rsum[16];

  const int tid = threadIdx.x;
  const int rr = tid >> 4;
  const int l16 = tid & 15;
  const int row = blockIdx.x * 16 + rr;
  const size_t obase = (size_t)row * DIM + l16 * 16;
  const float* cb_l = cb + (size_t)lvl * KCODES * DIM;
  const float* bv_l = bv + lvl * KCODES;

  // ---- phase A: residual via verified fl chain; stage row in LDS ----
  float4 xj[4], rj[4];
  {
    const float4* xp = reinterpret_cast<const float4*>(x + obase);
    #pragma unroll
    for (int j = 0; j < 4; ++j) { xj[j] = xp[j]; rj[j] = xj[j]; }
    for (int p = 0; p < lvl; ++p) {
      const float4* qp = reinterpret_cast<const float4*>(
          cb + ((size_t)p * KCODES + idxh[p * NROWS + row]) * DIM + l16 * 16);
      #pragma unroll
      for (int j = 0; j < 4; ++j) {
        float4 q = qp[j];
        rj[j].x -= q.x; rj[j].y -= q.y; rj[j].z -= q.z; rj[j].w -= q.w;
      }
    }
    #pragma unroll
    for (int j = 0; j < 4; ++j)
      *reinterpret_cast<float4*>(&rlds[rr][l16 * 16 + 4 * j]) = rj[j];
  }
  __syncthreads();

  // ---- phase B: exact chains on survivors ----
  const float A = rowsq[row];
  const unsigned n = counts[row];
  unsigned long long best = ~0ull;

#define CHAIN(CODE)                                                            \
  {                                                                            \
    const float* cp2 = cb_l + (size_t)(CODE) * DIM;                            \
    float a0 = 0.f;                                                            \
    _Pragma("unroll 8")                                                        \
    for (int dv = 0; dv < DIM / 4; ++dv) {                                     \
      float4 rv = *reinterpret_cast<const float4*>(&rlds[rr][dv * 4]);         \
      float4 cv = *reinterpret_cast<const float4*>(cp2 + dv * 4);              \
      a0 = fmaf(rv.x, cv.x, a0); a0 = fmaf(rv.y, cv.y, a0);                    \
      a0 = fmaf(rv.z, cv.z, a0); a0 = fmaf(rv.w, cv.w, a0);                    \
    }                                                                          \
    float t = A + bv_l[(CODE)];   /* fl(A + B) */                              \
    float dd = t - 2.0f * a0;     /* one rounding (2*dot exact) */             \
    unsigned long long pk =                                                    \
        ((unsigned long long)__float_as_uint(dd) << 32) | (unsigned)(CODE);    \
    best = (pk < best) ? pk : best;                                            \
  }

  if (n <= CAP) {
    for (unsigned s = l16; s < n; s += 16) {
      unsigned code = survq[(size_t)row * CAP + s];
      CHAIN(code);
    }
  } else {
    for (unsigned c = l16; c < KCODES; c += 16) CHAIN(c);  // safety net
  }
#undef CHAIN

  #pragma unroll
  for (int m = 1; m < 16; m <<= 1) {
    unsigned long long o = __shfl_xor(best, m);
    best = (o < best) ? o : best;
  }
  if (l16 == 0) {
    const int id = (int)(best & 0xffffffffull);
    idxh[lvl * NROWS + row] = id;
    fidx[lvl * NROWS + row] = (float)id;
    idsh[rr] = id;
  }
  __syncthreads();

  // ---- phase C: verified k_update math inline ----
  const int id = idsh[rr];
  const float4* cpc = reinterpret_cast<const float4*>(
      cb_l + (size_t)id * DIM + l16 * 16);
  float4* tp = reinterpret_cast<float4*>(tq + obase);
  float nn[16];
  float e = 0.f;
  #pragma unroll
  for (int j = 0; j < 4; ++j) {
    float4 c = cpc[j];
    float n0 = rj[j].x - c.x, n1 = rj[j].y - c.y;
    float n2 = rj[j].z - c.z, n3 = rj[j].w - c.w;
    nn[4 * j + 0] = n0; nn[4 * j + 1] = n1; nn[4 * j + 2] = n2; nn[4 * j + 3] = n3;
    e += (n0 * n0 + n1 * n1) + (n2 * n2 + n3 * n3);
    float4 tv;
    if (lvl == 0) {
      tv = c;
    } else {
      tv = tp[j];
      tv.x += c.x; tv.y += c.y; tv.z += c.z; tv.w += c.w;
    }
    if (lvl == 3) {
      tv.x = xj[j].x + (tv.x - xj[j].x); tv.y = xj[j].y + (tv.y - xj[j].y);
      tv.z = xj[j].z + (tv.z - xj[j].z); tv.w = xj[j].w + (tv.w - xj[j].w);
    }
    tp[j] = tv;
  }

  if (lvl < 3) {
    unsigned w[8];
    #pragma unroll
    for (int k = 0; k < 8; ++k)
      w[k] = (unsigned)f2bf(nn[2 * k]) | ((unsigned)f2bf(nn[2 * k + 1]) << 16);
    unsigned short* base = rhi + (size_t)blockIdx.x * 4096;
    const int ks = l16 >> 1;
    const int kb0 = (l16 & 1) * 2;
    *reinterpret_cast<uint4*>(base + ks * 512 + kb0 * 128 + rr * 8) =
        make_uint4(w[0], w[1], w[2], w[3]);
    *reinterpret_cast<uint4*>(base + ks * 512 + (kb0 + 1) * 128 + rr * 8) =
        make_uint4(w[4], w[5], w[6], w[7]);
  }

  sred[tid] = e;
  __syncthreads();
  if (tid < 16) {
    float s = 0.f;
    #pragma unroll
    for (int k = 0; k < 16; ++k) s += sred[tid * 16 + k];
    rsum[tid] = s;
    if (lvl < 3) rowsq_o[blockIdx.x * 16 + tid] = s;
  }
  __syncthreads();
  if (tid == 0) {
    float p = 0.f;
    #pragma unroll
    for (int k = 0; k < 16; ++k) p += rsum[k];
    part[blockIdx.x] = p;
  }
}

// ============ loss finalize (unchanged) ============
__global__ __launch_bounds__(256) void k_loss(const float* __restrict__ part,
                                              float* __restrict__ out) {
  __shared__ float s[256];
  const int tid = threadIdx.x;
  float means[4];
  for (int l = 0; l < 4; ++l) {
    float sum = 0.f;
    for (int i = tid; i < 2048; i += 256) sum += part[l * 2048 + i];
    s[tid] = sum;
    __syncthreads();
    for (int st = 128; st > 0; st >>= 1) {
      if (tid < st) s[tid] += s[tid + st];
      __syncthreads();
    }
    means[l] = s[0] * (1.0f / 8388608.0f);
    __syncthreads();
  }
  if (tid == 0) {
    float t = ((means[0] + means[1]) + means[2]) + means[3];
    float loss = t * 0.25f;
    out[0] = loss;
    out[1] = loss;
  }
}

extern "C" void kernel_launch(void* const* d_in, const int* in_sizes, int n_in,
                              void* d_out, int out_size, void* d_ws, size_t ws_size,
                              hipStream_t stream) {
  const float* x  = (const float*)d_in[0];
  const float* cb = (const float*)d_in[1];
  float* out = (float*)d_out;
  float* ws  = (float*)d_ws;

  // ws layout (float units)
  unsigned short* rhi = (unsigned short*)ws;                         // 4194304 f
  unsigned short* chi = (unsigned short*)(ws + 4194304);             // 524288 f
  unsigned* survq  = (unsigned*)(ws + 4194304 + 524288);             // 2097152 f
  unsigned* counts = (unsigned*)(ws + 4194304 + 524288 + 2097152);   // 32768 f
  int* idxh = (int*)(ws + 4194304 + 524288 + 2097152 + 131072);      // 131072 f
  float* bv    = ws + 4194304 + 524288 + 2097152 + 131072 + 131072;  // 4096
  float* rowsq = bv + 4096;                                          // 32768
  float* part  = rowsq + 32768;                                      // 8192

  float* tq      = out;                    // total_quant accumulates in d_out
  float* lossout = out + 8388608;
  float* fidx    = out + 8388610;

  k_bnorm<<<16, 256, 0, stream>>>(cb, bv);
  k_csplit<<<256, 256, 0, stream>>>(cb, chi);
  k_prep<<<2048, 256, 0, stream>>>(x, rhi, rowsq);

  for (int l = 0; l < NLEV; ++l) {
    k_screen<<<1024, 512, 0, stream>>>(rhi, chi + (size_t)l * KCODES * DIM,
                                       bv + l * KCODES, rowsq, survq, counts);
    k_exupd<<<2048, 256, 0, stream>>>(x, cb, bv, rowsq, survq, counts,
                                      idxh, fidx, tq, part + l * 2048,
                                      rowsq, rhi, l);
  }

  k_loss<<<1, 256, 0, stream>>>(part, lossout);
}

// Round 21
// 418.480 us; speedup vs baseline: 1.8363x; 1.0190x over previous
//
#include <hip/hip_runtime.h>

#define NROWS 32768   // B*T = 16*2048
#define DIM 256
#define KCODES 1024
#define NLEV 4
#define CAP 64
#define MARGIN 8e-3f

typedef short short8v __attribute__((ext_vector_type(8)));
typedef float f32x4v  __attribute__((ext_vector_type(4)));

// bf16 round-to-nearest-even
static __device__ __forceinline__ unsigned short f2bf(float f) {
  unsigned u = __float_as_uint(f);
  unsigned lsb = (u >> 16) & 1u;
  u += 0x7fffu + lsb;
  return (unsigned short)(u >> 16);
}

// Packed fragment layout (per 16-row/16-code tile of 256 dims = 4096 shorts):
//   pak[tile][ks*512 + kb*128 + r8*8 + j] = elem(row = tile*16 + r8,
//                                               k = ks*32 + kb*8 + j)
// Wave reads short8v at pak + tile*4096 + ks*512 + lane*8 -> contiguous 1 KB.

// ============ codebook squared norms (unchanged, verified) ============
__global__ __launch_bounds__(256) void k_bnorm(const float* __restrict__ cb,
                                               float* __restrict__ bv) {
  int r = blockIdx.x * blockDim.x + threadIdx.x;
  if (r >= NLEV * KCODES) return;
  const float4* p = reinterpret_cast<const float4*>(cb + (size_t)r * DIM);
  float s0 = 0.f, s1 = 0.f, s2 = 0.f, s3 = 0.f;
  for (int g = 0; g < DIM / 4; ++g) {
    float4 v = p[g];
    s0 += v.x * v.x; s1 += v.y * v.y; s2 += v.z * v.z; s3 += v.w * v.w;
  }
  bv[r] = (s0 + s1) + (s2 + s3);
}

// ============ codebook -> bf16, PACKED fragment layout (verified r15) ============
__global__ __launch_bounds__(256) void k_csplit(const float* __restrict__ cb,
                                                unsigned short* __restrict__ chi) {
  const int tid = threadIdx.x;
  const int cr = blockIdx.x * 16 + (tid >> 4);
  const int l16 = tid & 15;
  const float4* p = reinterpret_cast<const float4*>(cb + (size_t)cr * DIM + l16 * 16);
  unsigned w[8];
  #pragma unroll
  for (int j = 0; j < 4; ++j) {
    float4 v = p[j];
    w[2 * j + 0] = (unsigned)f2bf(v.x) | ((unsigned)f2bf(v.y) << 16);
    w[2 * j + 1] = (unsigned)f2bf(v.z) | ((unsigned)f2bf(v.w) << 16);
  }
  const int lvl_ = cr >> 10;
  const int c = cr & 1023;
  unsigned short* base = chi + (size_t)lvl_ * (KCODES * DIM) + (size_t)(c >> 4) * 4096;
  const int c8 = c & 15;
  const int ks = l16 >> 1;
  const int kb0 = (l16 & 1) * 2;
  *reinterpret_cast<uint4*>(base + ks * 512 + kb0 * 128 + c8 * 8) =
      make_uint4(w[0], w[1], w[2], w[3]);
  *reinterpret_cast<uint4*>(base + ks * 512 + (kb0 + 1) * 128 + c8 * 8) =
      make_uint4(w[4], w[5], w[6], w[7]);
}

// ============ x -> rowsq + rhi (PACKED, verified r15) ============
__global__ __launch_bounds__(256) void k_prep(const float* __restrict__ x,
                                              unsigned short* __restrict__ rhi,
                                              float* __restrict__ rowsq) {
  __shared__ float sred[256];
  const int tid = threadIdx.x;
  const int rr = tid >> 4;
  const int l16 = tid & 15;
  const int row = blockIdx.x * 16 + rr;
  const float4* p = reinterpret_cast<const float4*>(x + (size_t)row * DIM + l16 * 16);
  float e = 0.f;
  unsigned w[8];
  #pragma unroll
  for (int j = 0; j < 4; ++j) {
    float4 v = p[j];
    e += v.x * v.x + v.y * v.y + v.z * v.z + v.w * v.w;
    w[2 * j + 0] = (unsigned)f2bf(v.x) | ((unsigned)f2bf(v.y) << 16);
    w[2 * j + 1] = (unsigned)f2bf(v.z) | ((unsigned)f2bf(v.w) << 16);
  }
  unsigned short* base = rhi + (size_t)blockIdx.x * 4096;
  const int ks = l16 >> 1;
  const int kb0 = (l16 & 1) * 2;
  *reinterpret_cast<uint4*>(base + ks * 512 + kb0 * 128 + rr * 8) =
      make_uint4(w[0], w[1], w[2], w[3]);
  *reinterpret_cast<uint4*>(base + ks * 512 + (kb0 + 1) * 128 + rr * 8) =
      make_uint4(w[4], w[5], w[6], w[7]);
  sred[tid] = e;
  __syncthreads();
  if (tid < 16) {
    float s = 0.f;
    #pragma unroll
    for (int k = 0; k < 16; ++k) s += sred[tid * 16 + k];
    rowsq[blockIdx.x * 16 + tid] = s;
  }
}

// ============ MFMA bf16 screen: fenced packs + bounded 2-deep rotation ============
// 1024 blocks x 512 thr (8 waves). Block = 32 rows x 1024 codes; wave = 2
// row-tiles x 8 code-tiles (codes w*128..+127). r20's fenced load-pack (one
// latency per 10-load pack) + r16's bounded A/B set rotation (#pragma unroll 1
// -> only 2 packs live; no scratch spill). launch_bounds(512,2) gives a
// 256-reg budget for 2x40 VGPR sets + 64 AGPR acc. No barriers in main loop ->
// 8 independent waves/CU hide each pack's latency. Full-panel coverage ->
// block-local row min IS the global screen min (lean survivors). Fragments
// bit-identical to r12-r20.
__global__ __launch_bounds__(512, 2) void k_screen(const unsigned short* __restrict__ rhi,
                                                   const unsigned short* __restrict__ chi_l,
                                                   const float* __restrict__ bv_l,
                                                   const float* __restrict__ rowsq,
                                                   unsigned* __restrict__ survq,
                                                   unsigned* __restrict__ counts) {
  __shared__ float minb[32][8];
  __shared__ float rowminf[32];
  __shared__ unsigned cnt[32];
  const int tid = threadIdx.x;
  const int lane = tid & 63;
  const int w = tid >> 6;          // wave 0..7 -> codes w*128..+127
  const int rb = blockIdx.x;       // 32-row block
  const int row0 = rb * 32;
  const int c0 = w * 128;
  const int ln = lane & 15;
  const int kb = lane >> 4;

  f32x4v acc[2][8];
  #pragma unroll
  for (int r = 0; r < 2; ++r)
    #pragma unroll
    for (int t = 0; t < 8; ++t) acc[r][t] = (f32x4v){0.f, 0.f, 0.f, 0.f};

  const unsigned short* pa = rhi + (size_t)(rb * 2) * 4096 + lane * 8;
  const unsigned short* pb = chi_l + (size_t)(w * 8) * 4096 + lane * 8;

  short8v aA0, aA1, bA0, bA1, bA2, bA3, bA4, bA5, bA6, bA7;
  short8v aB0, aB1, bB0, bB1, bB2, bB3, bB4, bB5, bB6, bB7;

#define LOADSET(A0, A1, B0, B1, B2, B3, B4, B5, B6, B7, KS)                    \
  A0 = *reinterpret_cast<const short8v*>(pa + (KS) * 512);                     \
  A1 = *reinterpret_cast<const short8v*>(pa + 4096 + (KS) * 512);              \
  B0 = *reinterpret_cast<const short8v*>(pb + 0 * 4096 + (KS) * 512);          \
  B1 = *reinterpret_cast<const short8v*>(pb + 1 * 4096 + (KS) * 512);          \
  B2 = *reinterpret_cast<const short8v*>(pb + 2 * 4096 + (KS) * 512);          \
  B3 = *reinterpret_cast<const short8v*>(pb + 3 * 4096 + (KS) * 512);          \
  B4 = *reinterpret_cast<const short8v*>(pb + 4 * 4096 + (KS) * 512);          \
  B5 = *reinterpret_cast<const short8v*>(pb + 5 * 4096 + (KS) * 512);          \
  B6 = *reinterpret_cast<const short8v*>(pb + 6 * 4096 + (KS) * 512);          \
  B7 = *reinterpret_cast<const short8v*>(pb + 7 * 4096 + (KS) * 512);

#define MFMASET(A0, A1, B0, B1, B2, B3, B4, B5, B6, B7)                        \
  acc[0][0] = __builtin_amdgcn_mfma_f32_16x16x32_bf16(A0, B0, acc[0][0], 0, 0, 0); \
  acc[1][0] = __builtin_amdgcn_mfma_f32_16x16x32_bf16(A1, B0, acc[1][0], 0, 0, 0); \
  acc[0][1] = __builtin_amdgcn_mfma_f32_16x16x32_bf16(A0, B1, acc[0][1], 0, 0, 0); \
  acc[1][1] = __builtin_amdgcn_mfma_f32_16x16x32_bf16(A1, B1, acc[1][1], 0, 0, 0); \
  acc[0][2] = __builtin_amdgcn_mfma_f32_16x16x32_bf16(A0, B2, acc[0][2], 0, 0, 0); \
  acc[1][2] = __builtin_amdgcn_mfma_f32_16x16x32_bf16(A1, B2, acc[1][2], 0, 0, 0); \
  acc[0][3] = __builtin_amdgcn_mfma_f32_16x16x32_bf16(A0, B3, acc[0][3], 0, 0, 0); \
  acc[1][3] = __builtin_amdgcn_mfma_f32_16x16x32_bf16(A1, B3, acc[1][3], 0, 0, 0); \
  acc[0][4] = __builtin_amdgcn_mfma_f32_16x16x32_bf16(A0, B4, acc[0][4], 0, 0, 0); \
  acc[1][4] = __builtin_amdgcn_mfma_f32_16x16x32_bf16(A1, B4, acc[1][4], 0, 0, 0); \
  acc[0][5] = __builtin_amdgcn_mfma_f32_16x16x32_bf16(A0, B5, acc[0][5], 0, 0, 0); \
  acc[1][5] = __builtin_amdgcn_mfma_f32_16x16x32_bf16(A1, B5, acc[1][5], 0, 0, 0); \
  acc[0][6] = __builtin_amdgcn_mfma_f32_16x16x32_bf16(A0, B6, acc[0][6], 0, 0, 0); \
  acc[1][6] = __builtin_amdgcn_mfma_f32_16x16x32_bf16(A1, B6, acc[1][6], 0, 0, 0); \
  acc[0][7] = __builtin_amdgcn_mfma_f32_16x16x32_bf16(A0, B7, acc[0][7], 0, 0, 0); \
  acc[1][7] = __builtin_amdgcn_mfma_f32_16x16x32_bf16(A1, B7, acc[1][7], 0, 0, 0);

  // prologue: pack for ks=0 into set A
  LOADSET(aA0, aA1, bA0, bA1, bA2, bA3, bA4, bA5, bA6, bA7, 0)
  #pragma unroll 1
  for (int i = 0; i < 4; ++i) {
    // issue pack ks=2i+1 into set B, fence, consume set A
    LOADSET(aB0, aB1, bB0, bB1, bB2, bB3, bB4, bB5, bB6, bB7, 2 * i + 1)
    __builtin_amdgcn_sched_barrier(0);
    MFMASET(aA0, aA1, bA0, bA1, bA2, bA3, bA4, bA5, bA6, bA7)
    // issue pack ks=2i+2 into set A (except last), fence, consume set B
    if (i < 3) {
      LOADSET(aA0, aA1, bA0, bA1, bA2, bA3, bA4, bA5, bA6, bA7, 2 * i + 2)
    }
    __builtin_amdgcn_sched_barrier(0);
    MFMASET(aB0, aB1, bB0, bB1, bB2, bB3, bB4, bB5, bB6, bB7)
  }
#undef LOADSET
#undef MFMASET

  // per-row partial min over this wave's 128 codes
  float bvl[8];
  #pragma unroll
  for (int t = 0; t < 8; ++t) bvl[t] = bv_l[c0 + t * 16 + ln];
  float rq[2][4];
  #pragma unroll
  for (int r = 0; r < 2; ++r)
    #pragma unroll
    for (int g = 0; g < 4; ++g) rq[r][g] = rowsq[row0 + r * 16 + kb * 4 + g];

  #pragma unroll
  for (int r = 0; r < 2; ++r) {
    #pragma unroll
    for (int g = 0; g < 4; ++g) {
      float v = __builtin_inff();
      #pragma unroll
      for (int t = 0; t < 8; ++t) {
        float dd = (rq[r][g] + bvl[t]) - 2.0f * acc[r][t][g];
        v = fminf(v, dd);
      }
      #pragma unroll
      for (int m = 1; m < 16; m <<= 1) v = fminf(v, __shfl_xor(v, m));
      if (ln == 0) minb[r * 16 + kb * 4 + g][w] = v;
    }
  }
  __syncthreads();
  if (tid < 32) {
    float v = minb[tid][0];
    #pragma unroll
    for (int k = 1; k < 8; ++k) v = fminf(v, minb[tid][k]);
    rowminf[tid] = v;   // TRUE screen min over all 1024 codes
    cnt[tid] = 0;
  }
  __syncthreads();
  // survivor emission vs global screen min + MARGIN (r15/r20 semantics)
  #pragma unroll
  for (int r = 0; r < 2; ++r) {
    #pragma unroll
    for (int g = 0; g < 4; ++g) {
      const int rowloc = r * 16 + kb * 4 + g;
      const float thr = rowminf[rowloc] + MARGIN;
      #pragma unroll
      for (int t = 0; t < 8; ++t) {
        float dd = (rq[r][g] + bvl[t]) - 2.0f * acc[r][t][g];
        if (dd <= thr) {
          unsigned slot = atomicAdd(&cnt[rowloc], 1u);
          if (slot < CAP)
            survq[(size_t)(row0 + rowloc) * CAP + slot] =
                (unsigned)(c0 + t * 16 + ln);
        }
      }
    }
  }
  __syncthreads();
  if (tid < 32) counts[row0 + tid] = cnt[tid];
}

// ============ fused exact rescore + residual update (verified r14/r15/r20) ============
__global__ __launch_bounds__(256) void k_exupd(const float* __restrict__ x,
                                               const float* __restrict__ cb,
                                               const float* __restrict__ bv,
                                               const float* __restrict__ rowsq,
                                               const unsigned* __restrict__ survq,
                                               const unsigned* __restrict__ counts,
                                               int* __restrict__ idxh,
                                               float* __restrict__ fidx,
                                               float* __restrict__ tq,
                                               float* __restrict__ part,
                                               float* __restrict__ rowsq_o,
                                               unsigned short* __restrict__ rhi,
                                               int lvl) {
  __shared__ __align__(16) float rlds[16][260];
  __shared__ int idsh[16];
  __shared__ float sred[256];
  __shared__ float rsum[16];

  const int tid = threadIdx.x;
  const int rr = tid >> 4;
  const int l16 = tid & 15;
  const int row = blockIdx.x * 16 + rr;
  const size_t obase = (size_t)row * DIM + l16 * 16;
  const float* cb_l = cb + (size_t)lvl * KCODES * DIM;
  const float* bv_l = bv + lvl * KCODES;

  // ---- phase A: residual via verified fl chain; stage row in LDS ----
  float4 xj[4], rj[4];
  {
    const float4* xp = reinterpret_cast<const float4*>(x + obase);
    #pragma unroll
    for (int j = 0; j < 4; ++j) { xj[j] = xp[j]; rj[j] = xj[j]; }
    for (int p = 0; p < lvl; ++p) {
      const float4* qp = reinterpret_cast<const float4*>(
          cb + ((size_t)p * KCODES + idxh[p * NROWS + row]) * DIM + l16 * 16);
      #pragma unroll
      for (int j = 0; j < 4; ++j) {
        float4 q = qp[j];
        rj[j].x -= q.x; rj[j].y -= q.y; rj[j].z -= q.z; rj[j].w -= q.w;
      }
    }
    #pragma unroll
    for (int j = 0; j < 4; ++j)
      *reinterpret_cast<float4*>(&rlds[rr][l16 * 16 + 4 * j]) = rj[j];
  }
  __syncthreads();

  // ---- phase B: exact chains on survivors ----
  const float A = rowsq[row];
  const unsigned n = counts[row];
  unsigned long long best = ~0ull;

#define CHAIN(CODE)                                                            \
  {                                                                            \
    const float* cp2 = cb_l + (size_t)(CODE) * DIM;                            \
    float a0 = 0.f;                                                            \
    _Pragma("unroll 8")                                                        \
    for (int dv = 0; dv < DIM / 4; ++dv) {                                     \
      float4 rv = *reinterpret_cast<const float4*>(&rlds[rr][dv * 4]);         \
      float4 cv = *reinterpret_cast<const float4*>(cp2 + dv * 4);              \
      a0 = fmaf(rv.x, cv.x, a0); a0 = fmaf(rv.y, cv.y, a0);                    \
      a0 = fmaf(rv.z, cv.z, a0); a0 = fmaf(rv.w, cv.w, a0);                    \
    }                                                                          \
    float t = A + bv_l[(CODE)];   /* fl(A + B) */                              \
    float dd = t - 2.0f * a0;     /* one rounding (2*dot exact) */             \
    unsigned long long pk =                                                    \
        ((unsigned long long)__float_as_uint(dd) << 32) | (unsigned)(CODE);    \
    best = (pk < best) ? pk : best;                                            \
  }

  if (n <= CAP) {
    for (unsigned s = l16; s < n; s += 16) {
      unsigned code = survq[(size_t)row * CAP + s];
      CHAIN(code);
    }
  } else {
    for (unsigned c = l16; c < KCODES; c += 16) CHAIN(c);  // safety net
  }
#undef CHAIN

  #pragma unroll
  for (int m = 1; m < 16; m <<= 1) {
    unsigned long long o = __shfl_xor(best, m);
    best = (o < best) ? o : best;
  }
  if (l16 == 0) {
    const int id = (int)(best & 0xffffffffull);
    idxh[lvl * NROWS + row] = id;
    fidx[lvl * NROWS + row] = (float)id;
    idsh[rr] = id;
  }
  __syncthreads();

  // ---- phase C: verified k_update math inline ----
  const int id = idsh[rr];
  const float4* cpc = reinterpret_cast<const float4*>(
      cb_l + (size_t)id * DIM + l16 * 16);
  float4* tp = reinterpret_cast<float4*>(tq + obase);
  float nn[16];
  float e = 0.f;
  #pragma unroll
  for (int j = 0; j < 4; ++j) {
    float4 c = cpc[j];
    float n0 = rj[j].x - c.x, n1 = rj[j].y - c.y;
    float n2 = rj[j].z - c.z, n3 = rj[j].w - c.w;
    nn[4 * j + 0] = n0; nn[4 * j + 1] = n1; nn[4 * j + 2] = n2; nn[4 * j + 3] = n3;
    e += (n0 * n0 + n1 * n1) + (n2 * n2 + n3 * n3);
    float4 tv;
    if (lvl == 0) {
      tv = c;
    } else {
      tv = tp[j];
      tv.x += c.x; tv.y += c.y; tv.z += c.z; tv.w += c.w;
    }
    if (lvl == 3) {
      tv.x = xj[j].x + (tv.x - xj[j].x); tv.y = xj[j].y + (tv.y - xj[j].y);
      tv.z = xj[j].z + (tv.z - xj[j].z); tv.w = xj[j].w + (tv.w - xj[j].w);
    }
    tp[j] = tv;
  }

  if (lvl < 3) {
    unsigned w[8];
    #pragma unroll
    for (int k = 0; k < 8; ++k)
      w[k] = (unsigned)f2bf(nn[2 * k]) | ((unsigned)f2bf(nn[2 * k + 1]) << 16);
    unsigned short* base = rhi + (size_t)blockIdx.x * 4096;
    const int ks = l16 >> 1;
    const int kb0 = (l16 & 1) * 2;
    *reinterpret_cast<uint4*>(base + ks * 512 + kb0 * 128 + rr * 8) =
        make_uint4(w[0], w[1], w[2], w[3]);
    *reinterpret_cast<uint4*>(base + ks * 512 + (kb0 + 1) * 128 + rr * 8) =
        make_uint4(w[4], w[5], w[6], w[7]);
  }

  sred[tid] = e;
  __syncthreads();
  if (tid < 16) {
    float s = 0.f;
    #pragma unroll
    for (int k = 0; k < 16; ++k) s += sred[tid * 16 + k];
    rsum[tid] = s;
    if (lvl < 3) rowsq_o[blockIdx.x * 16 + tid] = s;
  }
  __syncthreads();
  if (tid == 0) {
    float p = 0.f;
    #pragma unroll
    for (int k = 0; k < 16; ++k) p += rsum[k];
    part[blockIdx.x] = p;
  }
}

// ============ loss finalize (unchanged) ============
__global__ __launch_bounds__(256) void k_loss(const float* __restrict__ part,
                                              float* __restrict__ out) {
  __shared__ float s[256];
  const int tid = threadIdx.x;
  float means[4];
  for (int l = 0; l < 4; ++l) {
    float sum = 0.f;
    for (int i = tid; i < 2048; i += 256) sum += part[l * 2048 + i];
    s[tid] = sum;
    __syncthreads();
    for (int st = 128; st > 0; st >>= 1) {
      if (tid < st) s[tid] += s[tid + st];
      __syncthreads();
    }
    means[l] = s[0] * (1.0f / 8388608.0f);
    __syncthreads();
  }
  if (tid == 0) {
    float t = ((means[0] + means[1]) + means[2]) + means[3];
    float loss = t * 0.25f;
    out[0] = loss;
    out[1] = loss;
  }
}

extern "C" void kernel_launch(void* const* d_in, const int* in_sizes, int n_in,
                              void* d_out, int out_size, void* d_ws, size_t ws_size,
                              hipStream_t stream) {
  const float* x  = (const float*)d_in[0];
  const float* cb = (const float*)d_in[1];
  float* out = (float*)d_out;
  float* ws  = (float*)d_ws;

  // ws layout (float units)
  unsigned short* rhi = (unsigned short*)ws;                         // 4194304 f
  unsigned short* chi = (unsigned short*)(ws + 4194304);             // 524288 f
  unsigned* survq  = (unsigned*)(ws + 4194304 + 524288);             // 2097152 f
  unsigned* counts = (unsigned*)(ws + 4194304 + 524288 + 2097152);   // 32768 f
  int* idxh = (int*)(ws + 4194304 + 524288 + 2097152 + 131072);      // 131072 f
  float* bv    = ws + 4194304 + 524288 + 2097152 + 131072 + 131072;  // 4096
  float* rowsq = bv + 4096;                                          // 32768
  float* part  = rowsq + 32768;                                      // 8192

  float* tq      = out;                    // total_quant accumulates in d_out
  float* lossout = out + 8388608;
  float* fidx    = out + 8388610;

  k_bnorm<<<16, 256, 0, stream>>>(cb, bv);
  k_csplit<<<256, 256, 0, stream>>>(cb, chi);
  k_prep<<<2048, 256, 0, stream>>>(x, rhi, rowsq);

  for (int l = 0; l < NLEV; ++l) {
    k_screen<<<1024, 512, 0, stream>>>(rhi, chi + (size_t)l * KCODES * DIM,
                                       bv + l * KCODES, rowsq, survq, counts);
    k_exupd<<<2048, 256, 0, stream>>>(x, cb, bv, rowsq, survq, counts,
                                      idxh, fidx, tq, part + l * 2048,
                                      rowsq, rhi, l);
  }

  k_loss<<<1, 256, 0, stream>>>(part, lossout);
}

// Round 22
// 415.249 us; speedup vs baseline: 1.8506x; 1.0078x over previous
//
#include <hip/hip_runtime.h>

#define NROWS 32768   // B*T = 16*2048
#define DIM 256
#define KCODES 1024
#define NLEV 4
#define CAP 64
#define MARGIN 8e-3f

typedef short short8v __attribute__((ext_vector_type(8)));
typedef float f32x4v  __attribute__((ext_vector_type(4)));

// bf16 round-to-nearest-even
static __device__ __forceinline__ unsigned short f2bf(float f) {
  unsigned u = __float_as_uint(f);
  unsigned lsb = (u >> 16) & 1u;
  u += 0x7fffu + lsb;
  return (unsigned short)(u >> 16);
}

// Packed fragment layout (per 16-row/16-code tile of 256 dims = 4096 shorts):
//   pak[tile][ks*512 + kb*128 + r8*8 + j] = elem(row = tile*16 + r8,
//                                               k = ks*32 + kb*8 + j)
// Wave reads short8v at pak + tile*4096 + ks*512 + lane*8 -> contiguous 1 KB.

// ============ codebook squared norms (unchanged, verified) ============
__global__ __launch_bounds__(256) void k_bnorm(const float* __restrict__ cb,
                                               float* __restrict__ bv) {
  int r = blockIdx.x * blockDim.x + threadIdx.x;
  if (r >= NLEV * KCODES) return;
  const float4* p = reinterpret_cast<const float4*>(cb + (size_t)r * DIM);
  float s0 = 0.f, s1 = 0.f, s2 = 0.f, s3 = 0.f;
  for (int g = 0; g < DIM / 4; ++g) {
    float4 v = p[g];
    s0 += v.x * v.x; s1 += v.y * v.y; s2 += v.z * v.z; s3 += v.w * v.w;
  }
  bv[r] = (s0 + s1) + (s2 + s3);
}

// ============ codebook -> bf16, PACKED fragment layout (verified r15) ============
__global__ __launch_bounds__(256) void k_csplit(const float* __restrict__ cb,
                                                unsigned short* __restrict__ chi) {
  const int tid = threadIdx.x;
  const int cr = blockIdx.x * 16 + (tid >> 4);
  const int l16 = tid & 15;
  const float4* p = reinterpret_cast<const float4*>(cb + (size_t)cr * DIM + l16 * 16);
  unsigned w[8];
  #pragma unroll
  for (int j = 0; j < 4; ++j) {
    float4 v = p[j];
    w[2 * j + 0] = (unsigned)f2bf(v.x) | ((unsigned)f2bf(v.y) << 16);
    w[2 * j + 1] = (unsigned)f2bf(v.z) | ((unsigned)f2bf(v.w) << 16);
  }
  const int lvl_ = cr >> 10;
  const int c = cr & 1023;
  unsigned short* base = chi + (size_t)lvl_ * (KCODES * DIM) + (size_t)(c >> 4) * 4096;
  const int c8 = c & 15;
  const int ks = l16 >> 1;
  const int kb0 = (l16 & 1) * 2;
  *reinterpret_cast<uint4*>(base + ks * 512 + kb0 * 128 + c8 * 8) =
      make_uint4(w[0], w[1], w[2], w[3]);
  *reinterpret_cast<uint4*>(base + ks * 512 + (kb0 + 1) * 128 + c8 * 8) =
      make_uint4(w[4], w[5], w[6], w[7]);
}

// ============ x -> rowsq + rhi (PACKED, verified r15) ============
__global__ __launch_bounds__(256) void k_prep(const float* __restrict__ x,
                                              unsigned short* __restrict__ rhi,
                                              float* __restrict__ rowsq) {
  __shared__ float sred[256];
  const int tid = threadIdx.x;
  const int rr = tid >> 4;
  const int l16 = tid & 15;
  const int row = blockIdx.x * 16 + rr;
  const float4* p = reinterpret_cast<const float4*>(x + (size_t)row * DIM + l16 * 16);
  float e = 0.f;
  unsigned w[8];
  #pragma unroll
  for (int j = 0; j < 4; ++j) {
    float4 v = p[j];
    e += v.x * v.x + v.y * v.y + v.z * v.z + v.w * v.w;
    w[2 * j + 0] = (unsigned)f2bf(v.x) | ((unsigned)f2bf(v.y) << 16);
    w[2 * j + 1] = (unsigned)f2bf(v.z) | ((unsigned)f2bf(v.w) << 16);
  }
  unsigned short* base = rhi + (size_t)blockIdx.x * 4096;
  const int ks = l16 >> 1;
  const int kb0 = (l16 & 1) * 2;
  *reinterpret_cast<uint4*>(base + ks * 512 + kb0 * 128 + rr * 8) =
      make_uint4(w[0], w[1], w[2], w[3]);
  *reinterpret_cast<uint4*>(base + ks * 512 + (kb0 + 1) * 128 + rr * 8) =
      make_uint4(w[4], w[5], w[6], w[7]);
  sred[tid] = e;
  __syncthreads();
  if (tid < 16) {
    float s = 0.f;
    #pragma unroll
    for (int k = 0; k < 16; ++k) s += sred[tid * 16 + k];
    rowsq[blockIdx.x * 16 + tid] = s;
  }
}

// ============ MFMA bf16 screen: fenced packs, 3-deep rotation ============
// 1024 blocks x 512 thr (8 waves). Block = 32 rows x 1024 codes; wave = 2
// row-tiles x 8 code-tiles. Fully-unrolled 8-step schedule with
// sched_barrier(0) pinning every {pack -> fence -> MFMA-set} region: exactly
// 3 packs in flight (3x40 VGPR + 64 AGPR acc -> fits launch_bounds(512,2)'s
// 256-reg budget, no spill), each MFMA-set waits for a pack issued ~2 compute
// phases earlier -> L2 latency covered. Consumed order ks=0..7 -> fragments
// and accumulation bit-identical to r20/r21 (absmax 0.0). Full-panel coverage
// -> block-local row min IS the global screen min (lean survivors).
__global__ __launch_bounds__(512, 2) void k_screen(const unsigned short* __restrict__ rhi,
                                                   const unsigned short* __restrict__ chi_l,
                                                   const float* __restrict__ bv_l,
                                                   const float* __restrict__ rowsq,
                                                   unsigned* __restrict__ survq,
                                                   unsigned* __restrict__ counts) {
  __shared__ float minb[32][8];
  __shared__ float rowminf[32];
  __shared__ unsigned cnt[32];
  const int tid = threadIdx.x;
  const int lane = tid & 63;
  const int w = tid >> 6;          // wave 0..7 -> codes w*128..+127
  const int rb = blockIdx.x;       // 32-row block
  const int row0 = rb * 32;
  const int c0 = w * 128;
  const int ln = lane & 15;
  const int kb = lane >> 4;

  f32x4v acc[2][8];
  #pragma unroll
  for (int r = 0; r < 2; ++r)
    #pragma unroll
    for (int t = 0; t < 8; ++t) acc[r][t] = (f32x4v){0.f, 0.f, 0.f, 0.f};

  const unsigned short* pa = rhi + (size_t)(rb * 2) * 4096 + lane * 8;
  const unsigned short* pb = chi_l + (size_t)(w * 8) * 4096 + lane * 8;

  short8v aA0, aA1, bA0, bA1, bA2, bA3, bA4, bA5, bA6, bA7;
  short8v aB0, aB1, bB0, bB1, bB2, bB3, bB4, bB5, bB6, bB7;
  short8v aC0, aC1, bC0, bC1, bC2, bC3, bC4, bC5, bC6, bC7;

#define LOADSET(S, KS)                                                         \
  a##S##0 = *reinterpret_cast<const short8v*>(pa + (KS) * 512);                \
  a##S##1 = *reinterpret_cast<const short8v*>(pa + 4096 + (KS) * 512);         \
  b##S##0 = *reinterpret_cast<const short8v*>(pb + 0 * 4096 + (KS) * 512);     \
  b##S##1 = *reinterpret_cast<const short8v*>(pb + 1 * 4096 + (KS) * 512);     \
  b##S##2 = *reinterpret_cast<const short8v*>(pb + 2 * 4096 + (KS) * 512);     \
  b##S##3 = *reinterpret_cast<const short8v*>(pb + 3 * 4096 + (KS) * 512);     \
  b##S##4 = *reinterpret_cast<const short8v*>(pb + 4 * 4096 + (KS) * 512);     \
  b##S##5 = *reinterpret_cast<const short8v*>(pb + 5 * 4096 + (KS) * 512);     \
  b##S##6 = *reinterpret_cast<const short8v*>(pb + 6 * 4096 + (KS) * 512);     \
  b##S##7 = *reinterpret_cast<const short8v*>(pb + 7 * 4096 + (KS) * 512);

#define MFMASET(S)                                                             \
  acc[0][0] = __builtin_amdgcn_mfma_f32_16x16x32_bf16(a##S##0, b##S##0, acc[0][0], 0, 0, 0); \
  acc[1][0] = __builtin_amdgcn_mfma_f32_16x16x32_bf16(a##S##1, b##S##0, acc[1][0], 0, 0, 0); \
  acc[0][1] = __builtin_amdgcn_mfma_f32_16x16x32_bf16(a##S##0, b##S##1, acc[0][1], 0, 0, 0); \
  acc[1][1] = __builtin_amdgcn_mfma_f32_16x16x32_bf16(a##S##1, b##S##1, acc[1][1], 0, 0, 0); \
  acc[0][2] = __builtin_amdgcn_mfma_f32_16x16x32_bf16(a##S##0, b##S##2, acc[0][2], 0, 0, 0); \
  acc[1][2] = __builtin_amdgcn_mfma_f32_16x16x32_bf16(a##S##1, b##S##2, acc[1][2], 0, 0, 0); \
  acc[0][3] = __builtin_amdgcn_mfma_f32_16x16x32_bf16(a##S##0, b##S##3, acc[0][3], 0, 0, 0); \
  acc[1][3] = __builtin_amdgcn_mfma_f32_16x16x32_bf16(a##S##1, b##S##3, acc[1][3], 0, 0, 0); \
  acc[0][4] = __builtin_amdgcn_mfma_f32_16x16x32_bf16(a##S##0, b##S##4, acc[0][4], 0, 0, 0); \
  acc[1][4] = __builtin_amdgcn_mfma_f32_16x16x32_bf16(a##S##1, b##S##4, acc[1][4], 0, 0, 0); \
  acc[0][5] = __builtin_amdgcn_mfma_f32_16x16x32_bf16(a##S##0, b##S##5, acc[0][5], 0, 0, 0); \
  acc[1][5] = __builtin_amdgcn_mfma_f32_16x16x32_bf16(a##S##1, b##S##5, acc[1][5], 0, 0, 0); \
  acc[0][6] = __builtin_amdgcn_mfma_f32_16x16x32_bf16(a##S##0, b##S##6, acc[0][6], 0, 0, 0); \
  acc[1][6] = __builtin_amdgcn_mfma_f32_16x16x32_bf16(a##S##1, b##S##6, acc[1][6], 0, 0, 0); \
  acc[0][7] = __builtin_amdgcn_mfma_f32_16x16x32_bf16(a##S##0, b##S##7, acc[0][7], 0, 0, 0); \
  acc[1][7] = __builtin_amdgcn_mfma_f32_16x16x32_bf16(a##S##1, b##S##7, acc[1][7], 0, 0, 0);

#define FENCE __builtin_amdgcn_sched_barrier(0)

  // 3-deep pipelined schedule, consumed order ks = 0..7
  LOADSET(A, 0)
  LOADSET(B, 1)
  LOADSET(C, 2)
  FENCE; MFMASET(A)
  LOADSET(A, 3)
  FENCE; MFMASET(B)
  LOADSET(B, 4)
  FENCE; MFMASET(C)
  LOADSET(C, 5)
  FENCE; MFMASET(A)
  LOADSET(A, 6)
  FENCE; MFMASET(B)
  LOADSET(B, 7)
  FENCE; MFMASET(C)
  FENCE; MFMASET(A)
  FENCE; MFMASET(B)
#undef LOADSET
#undef MFMASET
#undef FENCE

  // per-row partial min over this wave's 128 codes
  float bvl[8];
  #pragma unroll
  for (int t = 0; t < 8; ++t) bvl[t] = bv_l[c0 + t * 16 + ln];
  float rq[2][4];
  #pragma unroll
  for (int r = 0; r < 2; ++r)
    #pragma unroll
    for (int g = 0; g < 4; ++g) rq[r][g] = rowsq[row0 + r * 16 + kb * 4 + g];

  #pragma unroll
  for (int r = 0; r < 2; ++r) {
    #pragma unroll
    for (int g = 0; g < 4; ++g) {
      float v = __builtin_inff();
      #pragma unroll
      for (int t = 0; t < 8; ++t) {
        float dd = (rq[r][g] + bvl[t]) - 2.0f * acc[r][t][g];
        v = fminf(v, dd);
      }
      #pragma unroll
      for (int m = 1; m < 16; m <<= 1) v = fminf(v, __shfl_xor(v, m));
      if (ln == 0) minb[r * 16 + kb * 4 + g][w] = v;
    }
  }
  __syncthreads();
  if (tid < 32) {
    float v = minb[tid][0];
    #pragma unroll
    for (int k = 1; k < 8; ++k) v = fminf(v, minb[tid][k]);
    rowminf[tid] = v;   // TRUE screen min over all 1024 codes
    cnt[tid] = 0;
  }
  __syncthreads();
  // survivor emission vs global screen min + MARGIN (r15/r20/r21 semantics)
  #pragma unroll
  for (int r = 0; r < 2; ++r) {
    #pragma unroll
    for (int g = 0; g < 4; ++g) {
      const int rowloc = r * 16 + kb * 4 + g;
      const float thr = rowminf[rowloc] + MARGIN;
      #pragma unroll
      for (int t = 0; t < 8; ++t) {
        float dd = (rq[r][g] + bvl[t]) - 2.0f * acc[r][t][g];
        if (dd <= thr) {
          unsigned slot = atomicAdd(&cnt[rowloc], 1u);
          if (slot < CAP)
            survq[(size_t)(row0 + rowloc) * CAP + slot] =
                (unsigned)(c0 + t * 16 + ln);
        }
      }
    }
  }
  __syncthreads();
  if (tid < 32) counts[row0 + tid] = cnt[tid];
}

// ============ fused exact rescore + residual update (verified r14/r15/r20/r21) ============
__global__ __launch_bounds__(256) void k_exupd(const float* __restrict__ x,
                                               const float* __restrict__ cb,
                                               const float* __restrict__ bv,
                                               const float* __restrict__ rowsq,
                                               const unsigned* __restrict__ survq,
                                               const unsigned* __restrict__ counts,
                                               int* __restrict__ idxh,
                                               float* __restrict__ fidx,
                                               float* __restrict__ tq,
                                               float* __restrict__ part,
                                               float* __restrict__ rowsq_o,
                                               unsigned short* __restrict__ rhi,
                                               int lvl) {
  __shared__ __align__(16) float rlds[16][260];
  __shared__ int idsh[16];
  __shared__ float sred[256];
  __shared__ float rsum[16];

  const int tid = threadIdx.x;
  const int rr = tid >> 4;
  const int l16 = tid & 15;
  const int row = blockIdx.x * 16 + rr;
  const size_t obase = (size_t)row * DIM + l16 * 16;
  const float* cb_l = cb + (size_t)lvl * KCODES * DIM;
  const float* bv_l = bv + lvl * KCODES;

  // ---- phase A: residual via verified fl chain; stage row in LDS ----
  float4 xj[4], rj[4];
  {
    const float4* xp = reinterpret_cast<const float4*>(x + obase);
    #pragma unroll
    for (int j = 0; j < 4; ++j) { xj[j] = xp[j]; rj[j] = xj[j]; }
    for (int p = 0; p < lvl; ++p) {
      const float4* qp = reinterpret_cast<const float4*>(
          cb + ((size_t)p * KCODES + idxh[p * NROWS + row]) * DIM + l16 * 16);
      #pragma unroll
      for (int j = 0; j < 4; ++j) {
        float4 q = qp[j];
        rj[j].x -= q.x; rj[j].y -= q.y; rj[j].z -= q.z; rj[j].w -= q.w;
      }
    }
    #pragma unroll
    for (int j = 0; j < 4; ++j)
      *reinterpret_cast<float4*>(&rlds[rr][l16 * 16 + 4 * j]) = rj[j];
  }
  __syncthreads();

  // ---- phase B: exact chains on survivors ----
  const float A = rowsq[row];
  const unsigned n = counts[row];
  unsigned long long best = ~0ull;

#define CHAIN(CODE)                                                            \
  {                                                                            \
    const float* cp2 = cb_l + (size_t)(CODE) * DIM;                            \
    float a0 = 0.f;                                                            \
    _Pragma("unroll 8")                                                        \
    for (int dv = 0; dv < DIM / 4; ++dv) {                                     \
      float4 rv = *reinterpret_cast<const float4*>(&rlds[rr][dv * 4]);         \
      float4 cv = *reinterpret_cast<const float4*>(cp2 + dv * 4);              \
      a0 = fmaf(rv.x, cv.x, a0); a0 = fmaf(rv.y, cv.y, a0);                    \
      a0 = fmaf(rv.z, cv.z, a0); a0 = fmaf(rv.w, cv.w, a0);                    \
    }                                                                          \
    float t = A + bv_l[(CODE)];   /* fl(A + B) */                              \
    float dd = t - 2.0f * a0;     /* one rounding (2*dot exact) */             \
    unsigned long long pk =                                                    \
        ((unsigned long long)__float_as_uint(dd) << 32) | (unsigned)(CODE);    \
    best = (pk < best) ? pk : best;                                            \
  }

  if (n <= CAP) {
    for (unsigned s = l16; s < n; s += 16) {
      unsigned code = survq[(size_t)row * CAP + s];
      CHAIN(code);
    }
  } else {
    for (unsigned c = l16; c < KCODES; c += 16) CHAIN(c);  // safety net
  }
#undef CHAIN

  #pragma unroll
  for (int m = 1; m < 16; m <<= 1) {
    unsigned long long o = __shfl_xor(best, m);
    best = (o < best) ? o : best;
  }
  if (l16 == 0) {
    const int id = (int)(best & 0xffffffffull);
    idxh[lvl * NROWS + row] = id;
    fidx[lvl * NROWS + row] = (float)id;
    idsh[rr] = id;
  }
  __syncthreads();

  // ---- phase C: verified k_update math inline ----
  const int id = idsh[rr];
  const float4* cpc = reinterpret_cast<const float4*>(
      cb_l + (size_t)id * DIM + l16 * 16);
  float4* tp = reinterpret_cast<float4*>(tq + obase);
  float nn[16];
  float e = 0.f;
  #pragma unroll
  for (int j = 0; j < 4; ++j) {
    float4 c = cpc[j];
    float n0 = rj[j].x - c.x, n1 = rj[j].y - c.y;
    float n2 = rj[j].z - c.z, n3 = rj[j].w - c.w;
    nn[4 * j + 0] = n0; nn[4 * j + 1] = n1; nn[4 * j + 2] = n2; nn[4 * j + 3] = n3;
    e += (n0 * n0 + n1 * n1) + (n2 * n2 + n3 * n3);
    float4 tv;
    if (lvl == 0) {
      tv = c;
    } else {
      tv = tp[j];
      tv.x += c.x; tv.y += c.y; tv.z += c.z; tv.w += c.w;
    }
    if (lvl == 3) {
      tv.x = xj[j].x + (tv.x - xj[j].x); tv.y = xj[j].y + (tv.y - xj[j].y);
      tv.z = xj[j].z + (tv.z - xj[j].z); tv.w = xj[j].w + (tv.w - xj[j].w);
    }
    tp[j] = tv;
  }

  if (lvl < 3) {
    unsigned w[8];
    #pragma unroll
    for (int k = 0; k < 8; ++k)
      w[k] = (unsigned)f2bf(nn[2 * k]) | ((unsigned)f2bf(nn[2 * k + 1]) << 16);
    unsigned short* base = rhi + (size_t)blockIdx.x * 4096;
    const int ks = l16 >> 1;
    const int kb0 = (l16 & 1) * 2;
    *reinterpret_cast<uint4*>(base + ks * 512 + kb0 * 128 + rr * 8) =
        make_uint4(w[0], w[1], w[2], w[3]);
    *reinterpret_cast<uint4*>(base + ks * 512 + (kb0 + 1) * 128 + rr * 8) =
        make_uint4(w[4], w[5], w[6], w[7]);
  }

  sred[tid] = e;
  __syncthreads();
  if (tid < 16) {
    float s = 0.f;
    #pragma unroll
    for (int k = 0; k < 16; ++k) s += sred[tid * 16 + k];
    rsum[tid] = s;
    if (lvl < 3) rowsq_o[blockIdx.x * 16 + tid] = s;
  }
  __syncthreads();
  if (tid == 0) {
    float p = 0.f;
    #pragma unroll
    for (int k = 0; k < 16; ++k) p += rsum[k];
    part[blockIdx.x] = p;
  }
}

// ============ loss finalize (unchanged) ============
__global__ __launch_bounds__(256) void k_loss(const float* __restrict__ part,
                                              float* __restrict__ out) {
  __shared__ float s[256];
  const int tid = threadIdx.x;
  float means[4];
  for (int l = 0; l < 4; ++l) {
    float sum = 0.f;
    for (int i = tid; i < 2048; i += 256) sum += part[l * 2048 + i];
    s[tid] = sum;
    __syncthreads();
    for (int st = 128; st > 0; st >>= 1) {
      if (tid < st) s[tid] += s[tid + st];
      __syncthreads();
    }
    means[l] = s[0] * (1.0f / 8388608.0f);
    __syncthreads();
  }
  if (tid == 0) {
    float t = ((means[0] + means[1]) + means[2]) + means[3];
    float loss = t * 0.25f;
    out[0] = loss;
    out[1] = loss;
  }
}

extern "C" void kernel_launch(void* const* d_in, const int* in_sizes, int n_in,
                              void* d_out, int out_size, void* d_ws, size_t ws_size,
                              hipStream_t stream) {
  const float* x  = (const float*)d_in[0];
  const float* cb = (const float*)d_in[1];
  float* out = (float*)d_out;
  float* ws  = (float*)d_ws;

  // ws layout (float units)
  unsigned short* rhi = (unsigned short*)ws;                         // 4194304 f
  unsigned short* chi = (unsigned short*)(ws + 4194304);             // 524288 f
  unsigned* survq  = (unsigned*)(ws + 4194304 + 524288);             // 2097152 f
  unsigned* counts = (unsigned*)(ws + 4194304 + 524288 + 2097152);   // 32768 f
  int* idxh = (int*)(ws + 4194304 + 524288 + 2097152 + 131072);      // 131072 f
  float* bv    = ws + 4194304 + 524288 + 2097152 + 131072 + 131072;  // 4096
  float* rowsq = bv + 4096;                                          // 32768
  float* part  = rowsq + 32768;                                      // 8192

  float* tq      = out;                    // total_quant accumulates in d_out
  float* lossout = out + 8388608;
  float* fidx    = out + 8388610;

  k_bnorm<<<16, 256, 0, stream>>>(cb, bv);
  k_csplit<<<256, 256, 0, stream>>>(cb, chi);
  k_prep<<<2048, 256, 0, stream>>>(x, rhi, rowsq);

  for (int l = 0; l < NLEV; ++l) {
    k_screen<<<1024, 512, 0, stream>>>(rhi, chi + (size_t)l * KCODES * DIM,
                                       bv + l * KCODES, rowsq, survq, counts);
    k_exupd<<<2048, 256, 0, stream>>>(x, cb, bv, rowsq, survq, counts,
                                      idxh, fidx, tq, part + l * 2048,
                                      rowsq, rhi, l);
  }

  k_loss<<<1, 256, 0, stream>>>(part, lossout);
}

// Round 23
// 362.035 us; speedup vs baseline: 2.1226x; 1.1470x over previous
//
#include <hip/hip_runtime.h>

#define NROWS 32768   // B*T = 16*2048
#define DIM 256
#define KCODES 1024
#define NLEV 4
#define CAP 64
#define MARGIN 8e-3f

typedef short short8v __attribute__((ext_vector_type(8)));
typedef float f32x4v  __attribute__((ext_vector_type(4)));

// bf16 round-to-nearest-even
static __device__ __forceinline__ unsigned short f2bf(float f) {
  unsigned u = __float_as_uint(f);
  unsigned lsb = (u >> 16) & 1u;
  u += 0x7fffu + lsb;
  return (unsigned short)(u >> 16);
}

// Packed fragment layout (per 16-row/16-code tile of 256 dims = 4096 shorts):
//   pak[tile][ks*512 + kb*128 + r8*8 + j] = elem(row = tile*16 + r8,
//                                               k = ks*32 + kb*8 + j)
// Wave reads short8v at pak + tile*4096 + ks*512 + lane*8 -> contiguous 1 KB.

// ============ codebook squared norms (unchanged, verified) ============
__global__ __launch_bounds__(256) void k_bnorm(const float* __restrict__ cb,
                                               float* __restrict__ bv) {
  int r = blockIdx.x * blockDim.x + threadIdx.x;
  if (r >= NLEV * KCODES) return;
  const float4* p = reinterpret_cast<const float4*>(cb + (size_t)r * DIM);
  float s0 = 0.f, s1 = 0.f, s2 = 0.f, s3 = 0.f;
  for (int g = 0; g < DIM / 4; ++g) {
    float4 v = p[g];
    s0 += v.x * v.x; s1 += v.y * v.y; s2 += v.z * v.z; s3 += v.w * v.w;
  }
  bv[r] = (s0 + s1) + (s2 + s3);
}

// ============ codebook -> bf16, PACKED fragment layout (verified r15) ============
__global__ __launch_bounds__(256) void k_csplit(const float* __restrict__ cb,
                                                unsigned short* __restrict__ chi) {
  const int tid = threadIdx.x;
  const int cr = blockIdx.x * 16 + (tid >> 4);
  const int l16 = tid & 15;
  const float4* p = reinterpret_cast<const float4*>(cb + (size_t)cr * DIM + l16 * 16);
  unsigned w[8];
  #pragma unroll
  for (int j = 0; j < 4; ++j) {
    float4 v = p[j];
    w[2 * j + 0] = (unsigned)f2bf(v.x) | ((unsigned)f2bf(v.y) << 16);
    w[2 * j + 1] = (unsigned)f2bf(v.z) | ((unsigned)f2bf(v.w) << 16);
  }
  const int lvl_ = cr >> 10;
  const int c = cr & 1023;
  unsigned short* base = chi + (size_t)lvl_ * (KCODES * DIM) + (size_t)(c >> 4) * 4096;
  const int c8 = c & 15;
  const int ks = l16 >> 1;
  const int kb0 = (l16 & 1) * 2;
  *reinterpret_cast<uint4*>(base + ks * 512 + kb0 * 128 + c8 * 8) =
      make_uint4(w[0], w[1], w[2], w[3]);
  *reinterpret_cast<uint4*>(base + ks * 512 + (kb0 + 1) * 128 + c8 * 8) =
      make_uint4(w[4], w[5], w[6], w[7]);
}

// ============ x -> rowsq + rhi (PACKED, verified r15) ============
__global__ __launch_bounds__(256) void k_prep(const float* __restrict__ x,
                                              unsigned short* __restrict__ rhi,
                                              float* __restrict__ rowsq) {
  __shared__ float sred[256];
  const int tid = threadIdx.x;
  const int rr = tid >> 4;
  const int l16 = tid & 15;
  const int row = blockIdx.x * 16 + rr;
  const float4* p = reinterpret_cast<const float4*>(x + (size_t)row * DIM + l16 * 16);
  float e = 0.f;
  unsigned w[8];
  #pragma unroll
  for (int j = 0; j < 4; ++j) {
    float4 v = p[j];
    e += v.x * v.x + v.y * v.y + v.z * v.z + v.w * v.w;
    w[2 * j + 0] = (unsigned)f2bf(v.x) | ((unsigned)f2bf(v.y) << 16);
    w[2 * j + 1] = (unsigned)f2bf(v.z) | ((unsigned)f2bf(v.w) << 16);
  }
  unsigned short* base = rhi + (size_t)blockIdx.x * 4096;
  const int ks = l16 >> 1;
  const int kb0 = (l16 & 1) * 2;
  *reinterpret_cast<uint4*>(base + ks * 512 + kb0 * 128 + rr * 8) =
      make_uint4(w[0], w[1], w[2], w[3]);
  *reinterpret_cast<uint4*>(base + ks * 512 + (kb0 + 1) * 128 + rr * 8) =
      make_uint4(w[4], w[5], w[6], w[7]);
  sred[tid] = e;
  __syncthreads();
  if (tid < 16) {
    float s = 0.f;
    #pragma unroll
    for (int k = 0; k < 16; ++k) s += sred[tid * 16 + k];
    rowsq[blockIdx.x * 16 + tid] = s;
  }
}

// ============ MFMA bf16 screen: 1-deep fenced pack, 2 blocks/CU ============
// 1024 blocks x 512 thr (8 waves). Block = 32 rows x 1024 codes; wave = 2
// row-tiles x 8 code-tiles. r21/r22 showed 176 regs/wave -> 1 block/CU ->
// lockstep waves, zero TLP. Diet: ONE live pack (40 V) + acc 64 AGPR, cap via
// launch_bounds(512,4) (128 unified regs) -> 2 independent blocks/CU, 4
// waves/SIMD with interleaved phases hide pack latency. Per step: 10-load
// pack -> sched_barrier(0) -> 16 MFMA (the r20-proven batched interleave).
// Consumed order ks=0..7 -> fragments/accumulation bit-identical to r20-r22
// (absmax 0.0). Full-panel coverage -> block-local row min IS the global
// screen min (lean survivors).
__global__ __launch_bounds__(512, 4) void k_screen(const unsigned short* __restrict__ rhi,
                                                   const unsigned short* __restrict__ chi_l,
                                                   const float* __restrict__ bv_l,
                                                   const float* __restrict__ rowsq,
                                                   unsigned* __restrict__ survq,
                                                   unsigned* __restrict__ counts) {
  __shared__ float minb[32][8];
  __shared__ float rowminf[32];
  __shared__ unsigned cnt[32];
  const int tid = threadIdx.x;
  const int lane = tid & 63;
  const int w = tid >> 6;          // wave 0..7 -> codes w*128..+127
  const int rb = blockIdx.x;       // 32-row block
  const int row0 = rb * 32;
  const int c0 = w * 128;
  const int ln = lane & 15;
  const int kb = lane >> 4;

  f32x4v acc[2][8];
  #pragma unroll
  for (int r = 0; r < 2; ++r)
    #pragma unroll
    for (int t = 0; t < 8; ++t) acc[r][t] = (f32x4v){0.f, 0.f, 0.f, 0.f};

  const unsigned short* pa = rhi + (size_t)(rb * 2) * 4096 + lane * 8;
  const unsigned short* pb = chi_l + (size_t)(w * 8) * 4096 + lane * 8;

  #pragma unroll 1
  for (int ks = 0; ks < 8; ++ks) {
    // ---- load pack: 2 A + 8 B fragments, all independent ----
    short8v a0 = *reinterpret_cast<const short8v*>(pa + ks * 512);
    short8v a1 = *reinterpret_cast<const short8v*>(pa + 4096 + ks * 512);
    short8v b0 = *reinterpret_cast<const short8v*>(pb + 0 * 4096 + ks * 512);
    short8v b1 = *reinterpret_cast<const short8v*>(pb + 1 * 4096 + ks * 512);
    short8v b2 = *reinterpret_cast<const short8v*>(pb + 2 * 4096 + ks * 512);
    short8v b3 = *reinterpret_cast<const short8v*>(pb + 3 * 4096 + ks * 512);
    short8v b4 = *reinterpret_cast<const short8v*>(pb + 4 * 4096 + ks * 512);
    short8v b5 = *reinterpret_cast<const short8v*>(pb + 5 * 4096 + ks * 512);
    short8v b6 = *reinterpret_cast<const short8v*>(pb + 6 * 4096 + ks * 512);
    short8v b7 = *reinterpret_cast<const short8v*>(pb + 7 * 4096 + ks * 512);
    __builtin_amdgcn_sched_barrier(0);  // loads above, MFMAs below
    acc[0][0] = __builtin_amdgcn_mfma_f32_16x16x32_bf16(a0, b0, acc[0][0], 0, 0, 0);
    acc[1][0] = __builtin_amdgcn_mfma_f32_16x16x32_bf16(a1, b0, acc[1][0], 0, 0, 0);
    acc[0][1] = __builtin_amdgcn_mfma_f32_16x16x32_bf16(a0, b1, acc[0][1], 0, 0, 0);
    acc[1][1] = __builtin_amdgcn_mfma_f32_16x16x32_bf16(a1, b1, acc[1][1], 0, 0, 0);
    acc[0][2] = __builtin_amdgcn_mfma_f32_16x16x32_bf16(a0, b2, acc[0][2], 0, 0, 0);
    acc[1][2] = __builtin_amdgcn_mfma_f32_16x16x32_bf16(a1, b2, acc[1][2], 0, 0, 0);
    acc[0][3] = __builtin_amdgcn_mfma_f32_16x16x32_bf16(a0, b3, acc[0][3], 0, 0, 0);
    acc[1][3] = __builtin_amdgcn_mfma_f32_16x16x32_bf16(a1, b3, acc[1][3], 0, 0, 0);
    acc[0][4] = __builtin_amdgcn_mfma_f32_16x16x32_bf16(a0, b4, acc[0][4], 0, 0, 0);
    acc[1][4] = __builtin_amdgcn_mfma_f32_16x16x32_bf16(a1, b4, acc[1][4], 0, 0, 0);
    acc[0][5] = __builtin_amdgcn_mfma_f32_16x16x32_bf16(a0, b5, acc[0][5], 0, 0, 0);
    acc[1][5] = __builtin_amdgcn_mfma_f32_16x16x32_bf16(a1, b5, acc[1][5], 0, 0, 0);
    acc[0][6] = __builtin_amdgcn_mfma_f32_16x16x32_bf16(a0, b6, acc[0][6], 0, 0, 0);
    acc[1][6] = __builtin_amdgcn_mfma_f32_16x16x32_bf16(a1, b6, acc[1][6], 0, 0, 0);
    acc[0][7] = __builtin_amdgcn_mfma_f32_16x16x32_bf16(a0, b7, acc[0][7], 0, 0, 0);
    acc[1][7] = __builtin_amdgcn_mfma_f32_16x16x32_bf16(a1, b7, acc[1][7], 0, 0, 0);
  }

  // per-row partial min over this wave's 128 codes
  float bvl[8];
  #pragma unroll
  for (int t = 0; t < 8; ++t) bvl[t] = bv_l[c0 + t * 16 + ln];
  float rq[2][4];
  #pragma unroll
  for (int r = 0; r < 2; ++r)
    #pragma unroll
    for (int g = 0; g < 4; ++g) rq[r][g] = rowsq[row0 + r * 16 + kb * 4 + g];

  #pragma unroll
  for (int r = 0; r < 2; ++r) {
    #pragma unroll
    for (int g = 0; g < 4; ++g) {
      float v = __builtin_inff();
      #pragma unroll
      for (int t = 0; t < 8; ++t) {
        float dd = (rq[r][g] + bvl[t]) - 2.0f * acc[r][t][g];
        v = fminf(v, dd);
      }
      #pragma unroll
      for (int m = 1; m < 16; m <<= 1) v = fminf(v, __shfl_xor(v, m));
      if (ln == 0) minb[r * 16 + kb * 4 + g][w] = v;
    }
  }
  __syncthreads();
  if (tid < 32) {
    float v = minb[tid][0];
    #pragma unroll
    for (int k = 1; k < 8; ++k) v = fminf(v, minb[tid][k]);
    rowminf[tid] = v;   // TRUE screen min over all 1024 codes
    cnt[tid] = 0;
  }
  __syncthreads();
  // survivor emission vs global screen min + MARGIN (r15/r20-r22 semantics)
  #pragma unroll
  for (int r = 0; r < 2; ++r) {
    #pragma unroll
    for (int g = 0; g < 4; ++g) {
      const int rowloc = r * 16 + kb * 4 + g;
      const float thr = rowminf[rowloc] + MARGIN;
      #pragma unroll
      for (int t = 0; t < 8; ++t) {
        float dd = (rq[r][g] + bvl[t]) - 2.0f * acc[r][t][g];
        if (dd <= thr) {
          unsigned slot = atomicAdd(&cnt[rowloc], 1u);
          if (slot < CAP)
            survq[(size_t)(row0 + rowloc) * CAP + slot] =
                (unsigned)(c0 + t * 16 + ln);
        }
      }
    }
  }
  __syncthreads();
  if (tid < 32) counts[row0 + tid] = cnt[tid];
}

// ============ fused exact rescore + residual update (verified r14/r15/r20-r22) ============
__global__ __launch_bounds__(256) void k_exupd(const float* __restrict__ x,
                                               const float* __restrict__ cb,
                                               const float* __restrict__ bv,
                                               const float* __restrict__ rowsq,
                                               const unsigned* __restrict__ survq,
                                               const unsigned* __restrict__ counts,
                                               int* __restrict__ idxh,
                                               float* __restrict__ fidx,
                                               float* __restrict__ tq,
                                               float* __restrict__ part,
                                               float* __restrict__ rowsq_o,
                                               unsigned short* __restrict__ rhi,
                                               int lvl) {
  __shared__ __align__(16) float rlds[16][260];
  __shared__ int idsh[16];
  __shared__ float sred[256];
  __shared__ float rsum[16];

  const int tid = threadIdx.x;
  const int rr = tid >> 4;
  const int l16 = tid & 15;
  const int row = blockIdx.x * 16 + rr;
  const size_t obase = (size_t)row * DIM + l16 * 16;
  const float* cb_l = cb + (size_t)lvl * KCODES * DIM;
  const float* bv_l = bv + lvl * KCODES;

  // ---- phase A: residual via verified fl chain; stage row in LDS ----
  float4 xj[4], rj[4];
  {
    const float4* xp = reinterpret_cast<const float4*>(x + obase);
    #pragma unroll
    for (int j = 0; j < 4; ++j) { xj[j] = xp[j]; rj[j] = xj[j]; }
    for (int p = 0; p < lvl; ++p) {
      const float4* qp = reinterpret_cast<const float4*>(
          cb + ((size_t)p * KCODES + idxh[p * NROWS + row]) * DIM + l16 * 16);
      #pragma unroll
      for (int j = 0; j < 4; ++j) {
        float4 q = qp[j];
        rj[j].x -= q.x; rj[j].y -= q.y; rj[j].z -= q.z; rj[j].w -= q.w;
      }
    }
    #pragma unroll
    for (int j = 0; j < 4; ++j)
      *reinterpret_cast<float4*>(&rlds[rr][l16 * 16 + 4 * j]) = rj[j];
  }
  __syncthreads();

  // ---- phase B: exact chains on survivors ----
  const float A = rowsq[row];
  const unsigned n = counts[row];
  unsigned long long best = ~0ull;

#define CHAIN(CODE)                                                            \
  {                                                                            \
    const float* cp2 = cb_l + (size_t)(CODE) * DIM;                            \
    float a0 = 0.f;                                                            \
    _Pragma("unroll 8")                                                        \
    for (int dv = 0; dv < DIM / 4; ++dv) {                                     \
      float4 rv = *reinterpret_cast<const float4*>(&rlds[rr][dv * 4]);         \
      float4 cv = *reinterpret_cast<const float4*>(cp2 + dv * 4);              \
      a0 = fmaf(rv.x, cv.x, a0); a0 = fmaf(rv.y, cv.y, a0);                    \
      a0 = fmaf(rv.z, cv.z, a0); a0 = fmaf(rv.w, cv.w, a0);                    \
    }                                                                          \
    float t = A + bv_l[(CODE)];   /* fl(A + B) */                              \
    float dd = t - 2.0f * a0;     /* one rounding (2*dot exact) */             \
    unsigned long long pk =                                                    \
        ((unsigned long long)__float_as_uint(dd) << 32) | (unsigned)(CODE);    \
    best = (pk < best) ? pk : best;                                            \
  }

  if (n <= CAP) {
    for (unsigned s = l16; s < n; s += 16) {
      unsigned code = survq[(size_t)row * CAP + s];
      CHAIN(code);
    }
  } else {
    for (unsigned c = l16; c < KCODES; c += 16) CHAIN(c);  // safety net
  }
#undef CHAIN

  #pragma unroll
  for (int m = 1; m < 16; m <<= 1) {
    unsigned long long o = __shfl_xor(best, m);
    best = (o < best) ? o : best;
  }
  if (l16 == 0) {
    const int id = (int)(best & 0xffffffffull);
    idxh[lvl * NROWS + row] = id;
    fidx[lvl * NROWS + row] = (float)id;
    idsh[rr] = id;
  }
  __syncthreads();

  // ---- phase C: verified k_update math inline ----
  const int id = idsh[rr];
  const float4* cpc = reinterpret_cast<const float4*>(
      cb_l + (size_t)id * DIM + l16 * 16);
  float4* tp = reinterpret_cast<float4*>(tq + obase);
  float nn[16];
  float e = 0.f;
  #pragma unroll
  for (int j = 0; j < 4; ++j) {
    float4 c = cpc[j];
    float n0 = rj[j].x - c.x, n1 = rj[j].y - c.y;
    float n2 = rj[j].z - c.z, n3 = rj[j].w - c.w;
    nn[4 * j + 0] = n0; nn[4 * j + 1] = n1; nn[4 * j + 2] = n2; nn[4 * j + 3] = n3;
    e += (n0 * n0 + n1 * n1) + (n2 * n2 + n3 * n3);
    float4 tv;
    if (lvl == 0) {
      tv = c;
    } else {
      tv = tp[j];
      tv.x += c.x; tv.y += c.y; tv.z += c.z; tv.w += c.w;
    }
    if (lvl == 3) {
      tv.x = xj[j].x + (tv.x - xj[j].x); tv.y = xj[j].y + (tv.y - xj[j].y);
      tv.z = xj[j].z + (tv.z - xj[j].z); tv.w = xj[j].w + (tv.w - xj[j].w);
    }
    tp[j] = tv;
  }

  if (lvl < 3) {
    unsigned w[8];
    #pragma unroll
    for (int k = 0; k < 8; ++k)
      w[k] = (unsigned)f2bf(nn[2 * k]) | ((unsigned)f2bf(nn[2 * k + 1]) << 16);
    unsigned short* base = rhi + (size_t)blockIdx.x * 4096;
    const int ks = l16 >> 1;
    const int kb0 = (l16 & 1) * 2;
    *reinterpret_cast<uint4*>(base + ks * 512 + kb0 * 128 + rr * 8) =
        make_uint4(w[0], w[1], w[2], w[3]);
    *reinterpret_cast<uint4*>(base + ks * 512 + (kb0 + 1) * 128 + rr * 8) =
        make_uint4(w[4], w[5], w[6], w[7]);
  }

  sred[tid] = e;
  __syncthreads();
  if (tid < 16) {
    float s = 0.f;
    #pragma unroll
    for (int k = 0; k < 16; ++k) s += sred[tid * 16 + k];
    rsum[tid] = s;
    if (lvl < 3) rowsq_o[blockIdx.x * 16 + tid] = s;
  }
  __syncthreads();
  if (tid == 0) {
    float p = 0.f;
    #pragma unroll
    for (int k = 0; k < 16; ++k) p += rsum[k];
    part[blockIdx.x] = p;
  }
}

// ============ loss finalize (unchanged) ============
__global__ __launch_bounds__(256) void k_loss(const float* __restrict__ part,
                                              float* __restrict__ out) {
  __shared__ float s[256];
  const int tid = threadIdx.x;
  float means[4];
  for (int l = 0; l < 4; ++l) {
    float sum = 0.f;
    for (int i = tid; i < 2048; i += 256) sum += part[l * 2048 + i];
    s[tid] = sum;
    __syncthreads();
    for (int st = 128; st > 0; st >>= 1) {
      if (tid < st) s[tid] += s[tid + st];
      __syncthreads();
    }
    means[l] = s[0] * (1.0f / 8388608.0f);
    __syncthreads();
  }
  if (tid == 0) {
    float t = ((means[0] + means[1]) + means[2]) + means[3];
    float loss = t * 0.25f;
    out[0] = loss;
    out[1] = loss;
  }
}

extern "C" void kernel_launch(void* const* d_in, const int* in_sizes, int n_in,
                              void* d_out, int out_size, void* d_ws, size_t ws_size,
                              hipStream_t stream) {
  const float* x  = (const float*)d_in[0];
  const float* cb = (const float*)d_in[1];
  float* out = (float*)d_out;
  float* ws  = (float*)d_ws;

  // ws layout (float units)
  unsigned short* rhi = (unsigned short*)ws;                         // 4194304 f
  unsigned short* chi = (unsigned short*)(ws + 4194304);             // 524288 f
  unsigned* survq  = (unsigned*)(ws + 4194304 + 524288);             // 2097152 f
  unsigned* counts = (unsigned*)(ws + 4194304 + 524288 + 2097152);   // 32768 f
  int* idxh = (int*)(ws + 4194304 + 524288 + 2097152 + 131072);      // 131072 f
  float* bv    = ws + 4194304 + 524288 + 2097152 + 131072 + 131072;  // 4096
  float* rowsq = bv + 4096;                                          // 32768
  float* part  = rowsq + 32768;                                      // 8192

  float* tq      = out;                    // total_quant accumulates in d_out
  float* lossout = out + 8388608;
  float* fidx    = out + 8388610;

  k_bnorm<<<16, 256, 0, stream>>>(cb, bv);
  k_csplit<<<256, 256, 0, stream>>>(cb, chi);
  k_prep<<<2048, 256, 0, stream>>>(x, rhi, rowsq);

  for (int l = 0; l < NLEV; ++l) {
    k_screen<<<1024, 512, 0, stream>>>(rhi, chi + (size_t)l * KCODES * DIM,
                                       bv + l * KCODES, rowsq, survq, counts);
    k_exupd<<<2048, 256, 0, stream>>>(x, cb, bv, rowsq, survq, counts,
                                      idxh, fidx, tq, part + l * 2048,
                                      rowsq, rhi, l);
  }

  k_loss<<<1, 256, 0, stream>>>(part, lossout);
}

// Round 24
// 348.306 us; speedup vs baseline: 2.2063x; 1.0394x over previous
//
#include <hip/hip_runtime.h>

#define NROWS 32768   // B*T = 16*2048
#define DIM 256
#define KCODES 1024
#define NLEV 4
#define CAP 64
#define MARGIN 8e-3f

typedef short short8v __attribute__((ext_vector_type(8)));
typedef float f32x4v  __attribute__((ext_vector_type(4)));

// bf16 round-to-nearest-even
static __device__ __forceinline__ unsigned short f2bf(float f) {
  unsigned u = __float_as_uint(f);
  unsigned lsb = (u >> 16) & 1u;
  u += 0x7fffu + lsb;
  return (unsigned short)(u >> 16);
}

// Packed fragment layout (per 16-row/16-code tile of 256 dims = 4096 shorts):
//   pak[tile][ks*512 + kb*128 + r8*8 + j] = elem(row = tile*16 + r8,
//                                               k = ks*32 + kb*8 + j)
// Wave reads short8v at pak + tile*4096 + ks*512 + lane*8 -> contiguous 1 KB.

// ============ codebook squared norms (unchanged, verified) ============
__global__ __launch_bounds__(256) void k_bnorm(const float* __restrict__ cb,
                                               float* __restrict__ bv) {
  int r = blockIdx.x * blockDim.x + threadIdx.x;
  if (r >= NLEV * KCODES) return;
  const float4* p = reinterpret_cast<const float4*>(cb + (size_t)r * DIM);
  float s0 = 0.f, s1 = 0.f, s2 = 0.f, s3 = 0.f;
  for (int g = 0; g < DIM / 4; ++g) {
    float4 v = p[g];
    s0 += v.x * v.x; s1 += v.y * v.y; s2 += v.z * v.z; s3 += v.w * v.w;
  }
  bv[r] = (s0 + s1) + (s2 + s3);
}

// ============ codebook -> bf16, PACKED fragment layout (verified r15) ============
__global__ __launch_bounds__(256) void k_csplit(const float* __restrict__ cb,
                                                unsigned short* __restrict__ chi) {
  const int tid = threadIdx.x;
  const int cr = blockIdx.x * 16 + (tid >> 4);
  const int l16 = tid & 15;
  const float4* p = reinterpret_cast<const float4*>(cb + (size_t)cr * DIM + l16 * 16);
  unsigned w[8];
  #pragma unroll
  for (int j = 0; j < 4; ++j) {
    float4 v = p[j];
    w[2 * j + 0] = (unsigned)f2bf(v.x) | ((unsigned)f2bf(v.y) << 16);
    w[2 * j + 1] = (unsigned)f2bf(v.z) | ((unsigned)f2bf(v.w) << 16);
  }
  const int lvl_ = cr >> 10;
  const int c = cr & 1023;
  unsigned short* base = chi + (size_t)lvl_ * (KCODES * DIM) + (size_t)(c >> 4) * 4096;
  const int c8 = c & 15;
  const int ks = l16 >> 1;
  const int kb0 = (l16 & 1) * 2;
  *reinterpret_cast<uint4*>(base + ks * 512 + kb0 * 128 + c8 * 8) =
      make_uint4(w[0], w[1], w[2], w[3]);
  *reinterpret_cast<uint4*>(base + ks * 512 + (kb0 + 1) * 128 + c8 * 8) =
      make_uint4(w[4], w[5], w[6], w[7]);
}

// ============ x -> rowsq + rhi (PACKED, verified r15) ============
__global__ __launch_bounds__(256) void k_prep(const float* __restrict__ x,
                                              unsigned short* __restrict__ rhi,
                                              float* __restrict__ rowsq) {
  __shared__ float sred[256];
  const int tid = threadIdx.x;
  const int rr = tid >> 4;
  const int l16 = tid & 15;
  const int row = blockIdx.x * 16 + rr;
  const float4* p = reinterpret_cast<const float4*>(x + (size_t)row * DIM + l16 * 16);
  float e = 0.f;
  unsigned w[8];
  #pragma unroll
  for (int j = 0; j < 4; ++j) {
    float4 v = p[j];
    e += v.x * v.x + v.y * v.y + v.z * v.z + v.w * v.w;
    w[2 * j + 0] = (unsigned)f2bf(v.x) | ((unsigned)f2bf(v.y) << 16);
    w[2 * j + 1] = (unsigned)f2bf(v.z) | ((unsigned)f2bf(v.w) << 16);
  }
  unsigned short* base = rhi + (size_t)blockIdx.x * 4096;
  const int ks = l16 >> 1;
  const int kb0 = (l16 & 1) * 2;
  *reinterpret_cast<uint4*>(base + ks * 512 + kb0 * 128 + rr * 8) =
      make_uint4(w[0], w[1], w[2], w[3]);
  *reinterpret_cast<uint4*>(base + ks * 512 + (kb0 + 1) * 128 + rr * 8) =
      make_uint4(w[4], w[5], w[6], w[7]);
  sred[tid] = e;
  __syncthreads();
  if (tid < 16) {
    float s = 0.f;
    #pragma unroll
    for (int k = 0; k < 16; ++k) s += sred[tid * 16 + k];
    rowsq[blockIdx.x * 16 + tid] = s;
  }
}

// ============ MFMA bf16 screen: 1-deep fenced pack, 2 blocks/CU (verified r23) ============
__global__ __launch_bounds__(512, 4) void k_screen(const unsigned short* __restrict__ rhi,
                                                   const unsigned short* __restrict__ chi_l,
                                                   const float* __restrict__ bv_l,
                                                   const float* __restrict__ rowsq,
                                                   unsigned* __restrict__ survq,
                                                   unsigned* __restrict__ counts) {
  __shared__ float minb[32][8];
  __shared__ float rowminf[32];
  __shared__ unsigned cnt[32];
  const int tid = threadIdx.x;
  const int lane = tid & 63;
  const int w = tid >> 6;          // wave 0..7 -> codes w*128..+127
  const int rb = blockIdx.x;       // 32-row block
  const int row0 = rb * 32;
  const int c0 = w * 128;
  const int ln = lane & 15;
  const int kb = lane >> 4;

  f32x4v acc[2][8];
  #pragma unroll
  for (int r = 0; r < 2; ++r)
    #pragma unroll
    for (int t = 0; t < 8; ++t) acc[r][t] = (f32x4v){0.f, 0.f, 0.f, 0.f};

  const unsigned short* pa = rhi + (size_t)(rb * 2) * 4096 + lane * 8;
  const unsigned short* pb = chi_l + (size_t)(w * 8) * 4096 + lane * 8;

  #pragma unroll 1
  for (int ks = 0; ks < 8; ++ks) {
    short8v a0 = *reinterpret_cast<const short8v*>(pa + ks * 512);
    short8v a1 = *reinterpret_cast<const short8v*>(pa + 4096 + ks * 512);
    short8v b0 = *reinterpret_cast<const short8v*>(pb + 0 * 4096 + ks * 512);
    short8v b1 = *reinterpret_cast<const short8v*>(pb + 1 * 4096 + ks * 512);
    short8v b2 = *reinterpret_cast<const short8v*>(pb + 2 * 4096 + ks * 512);
    short8v b3 = *reinterpret_cast<const short8v*>(pb + 3 * 4096 + ks * 512);
    short8v b4 = *reinterpret_cast<const short8v*>(pb + 4 * 4096 + ks * 512);
    short8v b5 = *reinterpret_cast<const short8v*>(pb + 5 * 4096 + ks * 512);
    short8v b6 = *reinterpret_cast<const short8v*>(pb + 6 * 4096 + ks * 512);
    short8v b7 = *reinterpret_cast<const short8v*>(pb + 7 * 4096 + ks * 512);
    __builtin_amdgcn_sched_barrier(0);  // loads above, MFMAs below
    acc[0][0] = __builtin_amdgcn_mfma_f32_16x16x32_bf16(a0, b0, acc[0][0], 0, 0, 0);
    acc[1][0] = __builtin_amdgcn_mfma_f32_16x16x32_bf16(a1, b0, acc[1][0], 0, 0, 0);
    acc[0][1] = __builtin_amdgcn_mfma_f32_16x16x32_bf16(a0, b1, acc[0][1], 0, 0, 0);
    acc[1][1] = __builtin_amdgcn_mfma_f32_16x16x32_bf16(a1, b1, acc[1][1], 0, 0, 0);
    acc[0][2] = __builtin_amdgcn_mfma_f32_16x16x32_bf16(a0, b2, acc[0][2], 0, 0, 0);
    acc[1][2] = __builtin_amdgcn_mfma_f32_16x16x32_bf16(a1, b2, acc[1][2], 0, 0, 0);
    acc[0][3] = __builtin_amdgcn_mfma_f32_16x16x32_bf16(a0, b3, acc[0][3], 0, 0, 0);
    acc[1][3] = __builtin_amdgcn_mfma_f32_16x16x32_bf16(a1, b3, acc[1][3], 0, 0, 0);
    acc[0][4] = __builtin_amdgcn_mfma_f32_16x16x32_bf16(a0, b4, acc[0][4], 0, 0, 0);
    acc[1][4] = __builtin_amdgcn_mfma_f32_16x16x32_bf16(a1, b4, acc[1][4], 0, 0, 0);
    acc[0][5] = __builtin_amdgcn_mfma_f32_16x16x32_bf16(a0, b5, acc[0][5], 0, 0, 0);
    acc[1][5] = __builtin_amdgcn_mfma_f32_16x16x32_bf16(a1, b5, acc[1][5], 0, 0, 0);
    acc[0][6] = __builtin_amdgcn_mfma_f32_16x16x32_bf16(a0, b6, acc[0][6], 0, 0, 0);
    acc[1][6] = __builtin_amdgcn_mfma_f32_16x16x32_bf16(a1, b6, acc[1][6], 0, 0, 0);
    acc[0][7] = __builtin_amdgcn_mfma_f32_16x16x32_bf16(a0, b7, acc[0][7], 0, 0, 0);
    acc[1][7] = __builtin_amdgcn_mfma_f32_16x16x32_bf16(a1, b7, acc[1][7], 0, 0, 0);
  }

  // per-row partial min over this wave's 128 codes
  float bvl[8];
  #pragma unroll
  for (int t = 0; t < 8; ++t) bvl[t] = bv_l[c0 + t * 16 + ln];
  float rq[2][4];
  #pragma unroll
  for (int r = 0; r < 2; ++r)
    #pragma unroll
    for (int g = 0; g < 4; ++g) rq[r][g] = rowsq[row0 + r * 16 + kb * 4 + g];

  #pragma unroll
  for (int r = 0; r < 2; ++r) {
    #pragma unroll
    for (int g = 0; g < 4; ++g) {
      float v = __builtin_inff();
      #pragma unroll
      for (int t = 0; t < 8; ++t) {
        float dd = (rq[r][g] + bvl[t]) - 2.0f * acc[r][t][g];
        v = fminf(v, dd);
      }
      #pragma unroll
      for (int m = 1; m < 16; m <<= 1) v = fminf(v, __shfl_xor(v, m));
      if (ln == 0) minb[r * 16 + kb * 4 + g][w] = v;
    }
  }
  __syncthreads();
  if (tid < 32) {
    float v = minb[tid][0];
    #pragma unroll
    for (int k = 1; k < 8; ++k) v = fminf(v, minb[tid][k]);
    rowminf[tid] = v;   // TRUE screen min over all 1024 codes
    cnt[tid] = 0;
  }
  __syncthreads();
  // survivor emission vs global screen min + MARGIN (r15/r20-r23 semantics)
  #pragma unroll
  for (int r = 0; r < 2; ++r) {
    #pragma unroll
    for (int g = 0; g < 4; ++g) {
      const int rowloc = r * 16 + kb * 4 + g;
      const float thr = rowminf[rowloc] + MARGIN;
      #pragma unroll
      for (int t = 0; t < 8; ++t) {
        float dd = (rq[r][g] + bvl[t]) - 2.0f * acc[r][t][g];
        if (dd <= thr) {
          unsigned slot = atomicAdd(&cnt[rowloc], 1u);
          if (slot < CAP)
            survq[(size_t)(row0 + rowloc) * CAP + slot] =
                (unsigned)(c0 + t * 16 + ln);
        }
      }
    }
  }
  __syncthreads();
  if (tid < 32) counts[row0 + tid] = cnt[tid];
}

// ============ lean exact rescore + residual update (no tq stream) ============
// r23's verified k_exupd minus the total_quant read/accumulate/STE (moved to
// k_ste). Phases: A residual reconstruct (verified fl chain) -> B exact chains
// on survivors (verified) -> C nn/e/rhi/rowsq (verified math, tq dropped).
__global__ __launch_bounds__(256) void k_exupd(const float* __restrict__ x,
                                               const float* __restrict__ cb,
                                               const float* __restrict__ bv,
                                               const float* __restrict__ rowsq,
                                               const unsigned* __restrict__ survq,
                                               const unsigned* __restrict__ counts,
                                               int* __restrict__ idxh,
                                               float* __restrict__ fidx,
                                               float* __restrict__ part,
                                               float* __restrict__ rowsq_o,
                                               unsigned short* __restrict__ rhi,
                                               int lvl) {
  __shared__ __align__(16) float rlds[16][260];
  __shared__ int idsh[16];
  __shared__ float sred[256];
  __shared__ float rsum[16];

  const int tid = threadIdx.x;
  const int rr = tid >> 4;
  const int l16 = tid & 15;
  const int row = blockIdx.x * 16 + rr;
  const size_t obase = (size_t)row * DIM + l16 * 16;
  const float* cb_l = cb + (size_t)lvl * KCODES * DIM;
  const float* bv_l = bv + lvl * KCODES;

  // ---- phase A: residual via verified fl chain; stage row in LDS ----
  float4 rj[4];
  {
    const float4* xp = reinterpret_cast<const float4*>(x + obase);
    #pragma unroll
    for (int j = 0; j < 4; ++j) rj[j] = xp[j];
    for (int p = 0; p < lvl; ++p) {
      const float4* qp = reinterpret_cast<const float4*>(
          cb + ((size_t)p * KCODES + idxh[p * NROWS + row]) * DIM + l16 * 16);
      #pragma unroll
      for (int j = 0; j < 4; ++j) {
        float4 q = qp[j];
        rj[j].x -= q.x; rj[j].y -= q.y; rj[j].z -= q.z; rj[j].w -= q.w;
      }
    }
    #pragma unroll
    for (int j = 0; j < 4; ++j)
      *reinterpret_cast<float4*>(&rlds[rr][l16 * 16 + 4 * j]) = rj[j];
  }
  __syncthreads();

  // ---- phase B: exact chains on survivors (verified) ----
  const float A = rowsq[row];
  const unsigned n = counts[row];
  unsigned long long best = ~0ull;

#define CHAIN(CODE)                                                            \
  {                                                                            \
    const float* cp2 = cb_l + (size_t)(CODE) * DIM;                            \
    float a0 = 0.f;                                                            \
    _Pragma("unroll 8")                                                        \
    for (int dv = 0; dv < DIM / 4; ++dv) {                                     \
      float4 rv = *reinterpret_cast<const float4*>(&rlds[rr][dv * 4]);         \
      float4 cv = *reinterpret_cast<const float4*>(cp2 + dv * 4);              \
      a0 = fmaf(rv.x, cv.x, a0); a0 = fmaf(rv.y, cv.y, a0);                    \
      a0 = fmaf(rv.z, cv.z, a0); a0 = fmaf(rv.w, cv.w, a0);                    \
    }                                                                          \
    float t = A + bv_l[(CODE)];   /* fl(A + B) */                              \
    float dd = t - 2.0f * a0;     /* one rounding (2*dot exact) */             \
    unsigned long long pk =                                                    \
        ((unsigned long long)__float_as_uint(dd) << 32) | (unsigned)(CODE);    \
    best = (pk < best) ? pk : best;                                            \
  }

  if (n <= CAP) {
    for (unsigned s = l16; s < n; s += 16) {
      unsigned code = survq[(size_t)row * CAP + s];
      CHAIN(code);
    }
  } else {
    for (unsigned c = l16; c < KCODES; c += 16) CHAIN(c);  // safety net
  }
#undef CHAIN

  #pragma unroll
  for (int m = 1; m < 16; m <<= 1) {
    unsigned long long o = __shfl_xor(best, m);
    best = (o < best) ? o : best;
  }
  if (l16 == 0) {
    const int id = (int)(best & 0xffffffffull);
    idxh[lvl * NROWS + row] = id;
    fidx[lvl * NROWS + row] = (float)id;
    idsh[rr] = id;
  }
  __syncthreads();

  // ---- phase C (lean): nn, loss partial, next rhi, rowsq ----
  const int id = idsh[rr];
  const float4* cpc = reinterpret_cast<const float4*>(
      cb_l + (size_t)id * DIM + l16 * 16);
  float nn[16];
  float e = 0.f;
  #pragma unroll
  for (int j = 0; j < 4; ++j) {
    float4 c = cpc[j];
    float n0 = rj[j].x - c.x, n1 = rj[j].y - c.y;
    float n2 = rj[j].z - c.z, n3 = rj[j].w - c.w;
    nn[4 * j + 0] = n0; nn[4 * j + 1] = n1; nn[4 * j + 2] = n2; nn[4 * j + 3] = n3;
    e += (n0 * n0 + n1 * n1) + (n2 * n2 + n3 * n3);
  }

  if (lvl < 3) {
    unsigned w[8];
    #pragma unroll
    for (int k = 0; k < 8; ++k)
      w[k] = (unsigned)f2bf(nn[2 * k]) | ((unsigned)f2bf(nn[2 * k + 1]) << 16);
    unsigned short* base = rhi + (size_t)blockIdx.x * 4096;
    const int ks = l16 >> 1;
    const int kb0 = (l16 & 1) * 2;
    *reinterpret_cast<uint4*>(base + ks * 512 + kb0 * 128 + rr * 8) =
        make_uint4(w[0], w[1], w[2], w[3]);
    *reinterpret_cast<uint4*>(base + ks * 512 + (kb0 + 1) * 128 + rr * 8) =
        make_uint4(w[4], w[5], w[6], w[7]);
  }

  sred[tid] = e;
  __syncthreads();
  if (tid < 16) {
    float s = 0.f;
    #pragma unroll
    for (int k = 0; k < 16; ++k) s += sred[tid * 16 + k];
    rsum[tid] = s;
    if (lvl < 3) rowsq_o[blockIdx.x * 16 + tid] = s;
  }
  __syncthreads();
  if (tid == 0) {
    float p = 0.f;
    #pragma unroll
    for (int k = 0; k < 16; ++k) p += rsum[k];
    part[blockIdx.x] = p;
  }
}

// ============ final STE: out = x + (((c0+c1)+c2)+c3 - x) ============
// Same componentwise fl accumulation order as the verified per-level
// tq updates (lvl0: tv=c0; then tv+=c1; tv+=c2; tv+=c3) -> bit-identical.
__global__ __launch_bounds__(256) void k_ste(const float* __restrict__ x,
                                             const float* __restrict__ cb,
                                             const int* __restrict__ idxh,
                                             float* __restrict__ out) {
  const int tid = threadIdx.x;
  const int row = blockIdx.x * 16 + (tid >> 4);
  const int l16 = tid & 15;
  const size_t obase = (size_t)row * DIM + l16 * 16;
  const float4* c0p = reinterpret_cast<const float4*>(
      cb + ((size_t)0 * KCODES + idxh[0 * NROWS + row]) * DIM + l16 * 16);
  const float4* c1p = reinterpret_cast<const float4*>(
      cb + ((size_t)1 * KCODES + idxh[1 * NROWS + row]) * DIM + l16 * 16);
  const float4* c2p = reinterpret_cast<const float4*>(
      cb + ((size_t)2 * KCODES + idxh[2 * NROWS + row]) * DIM + l16 * 16);
  const float4* c3p = reinterpret_cast<const float4*>(
      cb + ((size_t)3 * KCODES + idxh[3 * NROWS + row]) * DIM + l16 * 16);
  const float4* xp = reinterpret_cast<const float4*>(x + obase);
  float4* op = reinterpret_cast<float4*>(out + obase);
  #pragma unroll
  for (int j = 0; j < 4; ++j) {
    float4 c0 = c0p[j], c1 = c1p[j], c2 = c2p[j], c3 = c3p[j], xv = xp[j];
    float4 tv;
    tv.x = c0.x; tv.y = c0.y; tv.z = c0.z; tv.w = c0.w;
    tv.x += c1.x; tv.y += c1.y; tv.z += c1.z; tv.w += c1.w;
    tv.x += c2.x; tv.y += c2.y; tv.z += c2.z; tv.w += c2.w;
    tv.x += c3.x; tv.y += c3.y; tv.z += c3.z; tv.w += c3.w;
    tv.x = xv.x + (tv.x - xv.x); tv.y = xv.y + (tv.y - xv.y);
    tv.z = xv.z + (tv.z - xv.z); tv.w = xv.w + (tv.w - xv.w);
    op[j] = tv;
  }
}

// ============ loss finalize (unchanged) ============
__global__ __launch_bounds__(256) void k_loss(const float* __restrict__ part,
                                              float* __restrict__ out) {
  __shared__ float s[256];
  const int tid = threadIdx.x;
  float means[4];
  for (int l = 0; l < 4; ++l) {
    float sum = 0.f;
    for (int i = tid; i < 2048; i += 256) sum += part[l * 2048 + i];
    s[tid] = sum;
    __syncthreads();
    for (int st = 128; st > 0; st >>= 1) {
      if (tid < st) s[tid] += s[tid + st];
      __syncthreads();
    }
    means[l] = s[0] * (1.0f / 8388608.0f);
    __syncthreads();
  }
  if (tid == 0) {
    float t = ((means[0] + means[1]) + means[2]) + means[3];
    float loss = t * 0.25f;
    out[0] = loss;
    out[1] = loss;
  }
}

extern "C" void kernel_launch(void* const* d_in, const int* in_sizes, int n_in,
                              void* d_out, int out_size, void* d_ws, size_t ws_size,
                              hipStream_t stream) {
  const float* x  = (const float*)d_in[0];
  const float* cb = (const float*)d_in[1];
  float* out = (float*)d_out;
  float* ws  = (float*)d_ws;

  // ws layout (float units)
  unsigned short* rhi = (unsigned short*)ws;                         // 4194304 f
  unsigned short* chi = (unsigned short*)(ws + 4194304);             // 524288 f
  unsigned* survq  = (unsigned*)(ws + 4194304 + 524288);             // 2097152 f
  unsigned* counts = (unsigned*)(ws + 4194304 + 524288 + 2097152);   // 32768 f
  int* idxh = (int*)(ws + 4194304 + 524288 + 2097152 + 131072);      // 131072 f
  float* bv    = ws + 4194304 + 524288 + 2097152 + 131072 + 131072;  // 4096
  float* rowsq = bv + 4096;                                          // 32768
  float* part  = rowsq + 32768;                                      // 8192

  float* lossout = out + 8388608;
  float* fidx    = out + 8388610;

  k_bnorm<<<16, 256, 0, stream>>>(cb, bv);
  k_csplit<<<256, 256, 0, stream>>>(cb, chi);
  k_prep<<<2048, 256, 0, stream>>>(x, rhi, rowsq);

  for (int l = 0; l < NLEV; ++l) {
    k_screen<<<1024, 512, 0, stream>>>(rhi, chi + (size_t)l * KCODES * DIM,
                                       bv + l * KCODES, rowsq, survq, counts);
    k_exupd<<<2048, 256, 0, stream>>>(x, cb, bv, rowsq, survq, counts,
                                      idxh, fidx, part + l * 2048,
                                      rowsq, rhi, l);
  }

  k_ste<<<2048, 256, 0, stream>>>(x, cb, idxh, out);
  k_loss<<<1, 256, 0, stream>>>(part, lossout);
}